// Round 1
// baseline (499.495 us; speedup 1.0000x reference)
//
#include <hip/hip_runtime.h>
#include <hip/hip_bf16.h>
#include <math.h>

// Problem constants
#define S_LEN 2048
#define BATCH 2
#define DMODEL 512
#define NHEAD 8
#define DHEAD 64
#define ROWS (S_LEN * BATCH)      // 4096
#define CHUNK 64
#define NCHUNK (S_LEN / CHUNK)    // 32
#define NCHAIN (BATCH * NHEAD)    // 16
#define SCALE 0.125f
#define EPS 1e-5f
#define LN_EPS 1e-5f

__device__ __forceinline__ float elu1(float x) {
    // jax.nn.elu(x) + 1 == (x > 0 ? x + 1 : exp(x))
    return x > 0.0f ? x + 1.0f : __expf(x);
}

// C[M,N] = act(A[M,K] @ B[K,N]); all row-major with given leading dims.
// 64x64 block tile, BK=16, 256 threads, 4x4 microtile per thread.
template <int ACT>
__global__ void gemm_kernel(const float* __restrict__ A, int lda,
                            const float* __restrict__ B, int ldb,
                            float* __restrict__ C, int ldc, int K) {
    __shared__ float As[16][64];
    __shared__ float Bs[16][64];
    const int tid = threadIdx.x;
    const int tx = tid & 15;   // -> n
    const int ty = tid >> 4;   // -> m
    const int m0 = blockIdx.y * 64;
    const int n0 = blockIdx.x * 64;
    float acc[4][4] = {};
    for (int kt = 0; kt < K; kt += 16) {
        {
            int L = tid;
#pragma unroll
            for (int r = 0; r < 4; ++r) {
                int k = L & 15, m = L >> 4;
                As[k][m] = A[(m0 + m) * lda + kt + k];
                L += 256;
            }
        }
        {
            int L = tid;
#pragma unroll
            for (int r = 0; r < 4; ++r) {
                int n = L & 63, k = L >> 6;
                Bs[k][n] = B[(kt + k) * ldb + n0 + n];
                L += 256;
            }
        }
        __syncthreads();
#pragma unroll
        for (int k = 0; k < 16; ++k) {
            float a[4], b[4];
#pragma unroll
            for (int i = 0; i < 4; ++i) a[i] = As[k][ty * 4 + i];
#pragma unroll
            for (int j = 0; j < 4; ++j) b[j] = Bs[k][tx * 4 + j];
#pragma unroll
            for (int i = 0; i < 4; ++i)
#pragma unroll
                for (int j = 0; j < 4; ++j)
                    acc[i][j] = fmaf(a[i], b[j], acc[i][j]);
        }
        __syncthreads();
    }
#pragma unroll
    for (int i = 0; i < 4; ++i) {
        int m = m0 + ty * 4 + i;
#pragma unroll
        for (int j = 0; j < 4; ++j) {
            int n = n0 + tx * 4 + j;
            float v = acc[i][j];
            if (ACT) v = elu1(v);
            C[m * ldc + n] = v;
        }
    }
}

// Per (chain, chunk): KVc = sum_j k_j v_j^T (64x64), KSc = sum_j k_j (64)
__global__ void chunk_kv_kernel(const float* __restrict__ Kf,
                                const float* __restrict__ Vf,
                                float* __restrict__ KVc,
                                float* __restrict__ KSc) {
    __shared__ float Kl[CHUNK][DHEAD];
    __shared__ float Vl[CHUNK][DHEAD];
    const int c = blockIdx.x, chain = blockIdx.y;
    const int b = chain / NHEAD, hh = chain % NHEAD;
    const int tid = threadIdx.x;
    for (int L = tid; L < CHUNK * DHEAD; L += 256) {
        int j = L >> 6, d = L & 63;
        int row = (c * CHUNK + j) * BATCH + b;
        int col = hh * DHEAD + d;
        Kl[j][d] = Kf[row * DMODEL + col];
        Vl[j][d] = Vf[row * DMODEL + col];
    }
    __syncthreads();
    const int lane = tid & 63, wave = tid >> 6;
    float* kvout = KVc + (chain * NCHUNK + c) * (DHEAD * DHEAD);
#pragma unroll
    for (int t = 0; t < 16; ++t) {
        int dk = wave + t * 4;  // wave-uniform -> broadcast reads of Kl
        int dv = lane;
        float acc = 0.f;
#pragma unroll 8
        for (int j = 0; j < CHUNK; ++j)
            acc = fmaf(Kl[j][dk], Vl[j][dv], acc);
        kvout[dk * DHEAD + dv] = acc;
    }
    if (tid < DHEAD) {
        float s = 0.f;
        for (int j = 0; j < CHUNK; ++j) s += Kl[j][tid];
        KSc[(chain * NCHUNK + c) * DHEAD + tid] = s;
    }
}

// Per (chain, chunk): out_i = SCALE*(q_i^T M_prev + sum_{j<=i in chunk} (q_i.k_j) v_j)
//                          / (SCALE*(q_i.Sprev + sum_{j<=i} q_i.k_j) + EPS)
__global__ void attn_chunk_kernel(const float* __restrict__ Qf,
                                  const float* __restrict__ Kf,
                                  const float* __restrict__ Vf,
                                  const float* __restrict__ KVc,
                                  const float* __restrict__ KSc,
                                  float* __restrict__ ATT) {
    __shared__ float Ql[CHUNK][DHEAD];
    __shared__ float Kl[CHUNK][DHEAD + 1];  // +1 pad: score phase reads Kl[lane][d]
    __shared__ float Vl[CHUNK][DHEAD];
    __shared__ float Mp[DHEAD][DHEAD];
    __shared__ float Sc[CHUNK][CHUNK];
    __shared__ float Sprev[DHEAD];
    const int c = blockIdx.x, chain = blockIdx.y;
    const int b = chain / NHEAD, hh = chain % NHEAD;
    const int tid = threadIdx.x;
    const int lane = tid & 63, wave = tid >> 6;

    // accumulate prefix state over previous chunks (registers -> LDS)
    float macc[16];
#pragma unroll
    for (int t = 0; t < 16; ++t) macc[t] = 0.f;
    float sacc = 0.f;
    for (int p = 0; p < c; ++p) {
        const float* kv = KVc + (chain * NCHUNK + p) * (DHEAD * DHEAD);
#pragma unroll
        for (int t = 0; t < 16; ++t)
            macc[t] += kv[(wave + t * 4) * DHEAD + lane];
        if (tid < DHEAD) sacc += KSc[(chain * NCHUNK + p) * DHEAD + tid];
    }
#pragma unroll
    for (int t = 0; t < 16; ++t) Mp[wave + t * 4][lane] = macc[t];
    if (tid < DHEAD) Sprev[tid] = sacc;

    // load Q,K,V chunk
    for (int L = tid; L < CHUNK * DHEAD; L += 256) {
        int j = L >> 6, d = L & 63;
        int row = (c * CHUNK + j) * BATCH + b;
        int col = hh * DHEAD + d;
        Ql[j][d] = Qf[row * DMODEL + col];
        Kl[j][d] = Kf[row * DMODEL + col];
        Vl[j][d] = Vf[row * DMODEL + col];
    }
    __syncthreads();

    // intra-chunk raw scores (causal within chunk)
#pragma unroll
    for (int t = 0; t < 16; ++t) {
        int i = wave + t * 4;  // wave-uniform
        int j = lane;
        float s = 0.f;
        if (j <= i) {
#pragma unroll 8
            for (int d = 0; d < DHEAD; ++d)
                s = fmaf(Ql[i][d], Kl[j][d], s);
        }
        Sc[i][j] = s;
    }
    __syncthreads();

    // combine intra + inter, normalize, write
#pragma unroll
    for (int t = 0; t < 16; ++t) {
        int i = wave + t * 4;  // wave-uniform
        int dv = lane;
        float num = 0.f, den = 0.f;
        for (int j = 0; j < CHUNK; ++j) {
            float w = Sc[i][j];
            num = fmaf(w, Vl[j][dv], num);
            den += w;
        }
        float num2 = 0.f, den2 = 0.f;
#pragma unroll 8
        for (int dk = 0; dk < DHEAD; ++dk) {
            float q = Ql[i][dk];
            num2 = fmaf(q, Mp[dk][dv], num2);
            den2 = fmaf(q, Sprev[dk], den2);
        }
        float denom = SCALE * (den + den2) + EPS;
        float outv = SCALE * (num + num2) / denom;
        int row = (c * CHUNK + i) * BATCH + b;
        ATT[row * DMODEL + hh * DHEAD + dv] = outv;
    }
}

// out = LayerNorm(h + attn_out) ; one wave per row of 512
__global__ void ln_kernel(const float* __restrict__ h,
                          const float* __restrict__ AO,
                          const float* __restrict__ gamma,
                          const float* __restrict__ beta,
                          float* __restrict__ out) {
    const int tid = threadIdx.x;
    const int lane = tid & 63, wave = tid >> 6;
    const int row = blockIdx.x * 4 + wave;
    float v[8];
    float sum = 0.f;
#pragma unroll
    for (int i = 0; i < 8; ++i) {
        int col = lane + i * 64;
        float x = h[row * DMODEL + col] + AO[row * DMODEL + col];
        v[i] = x;
        sum += x;
    }
#pragma unroll
    for (int off = 32; off >= 1; off >>= 1) sum += __shfl_xor(sum, off, 64);
    float mean = sum * (1.f / DMODEL);
    float var = 0.f;
#pragma unroll
    for (int i = 0; i < 8; ++i) {
        float d = v[i] - mean;
        var = fmaf(d, d, var);
    }
#pragma unroll
    for (int off = 32; off >= 1; off >>= 1) var += __shfl_xor(var, off, 64);
    float rstd = rsqrtf(var * (1.f / DMODEL) + LN_EPS);
#pragma unroll
    for (int i = 0; i < 8; ++i) {
        int col = lane + i * 64;
        out[row * DMODEL + col] = (v[i] - mean) * rstd * gamma[col] + beta[col];
    }
}

extern "C" void kernel_launch(void* const* d_in, const int* in_sizes, int n_in,
                              void* d_out, int out_size, void* d_ws, size_t ws_size,
                              hipStream_t stream) {
    const float* h = (const float*)d_in[0];
    const float* Wq = (const float*)d_in[1];
    const float* Wkv = (const float*)d_in[2];
    const float* Wo = (const float*)d_in[3];
    const float* gamma = (const float*)d_in[4];
    const float* beta = (const float*)d_in[5];
    // d_in[6] = attn_mask (causal) -- structure known, not needed

    float* ws = (float*)d_ws;
    float* Q = ws;                    // [4096][512]
    float* Kf = ws + 2097152;         // [4096][512]
    float* Vf = ws + 4194304;         // [4096][512]
    float* ATT = ws + 6291456;        // [4096][512]
    float* KVc = ws + 8388608;        // [16][32][64][64]
    float* KSc = ws + 10485760;       // [16][32][64]
    float* AO = Q;                    // reuse Q buffer for attn_out

    dim3 blk(256);
    // Q = elu1(h @ Wq)
    gemm_kernel<1><<<dim3(8, 64), blk, 0, stream>>>(h, 512, Wq, 512, Q, 512, 512);
    // K = elu1(h @ Wkv[:, :512])
    gemm_kernel<1><<<dim3(8, 64), blk, 0, stream>>>(h, 512, Wkv, 1024, Kf, 512, 512);
    // V = h @ Wkv[:, 512:]
    gemm_kernel<0><<<dim3(8, 64), blk, 0, stream>>>(h, 512, Wkv + 512, 1024, Vf, 512, 512);
    // per-chunk KV outer products and K sums
    chunk_kv_kernel<<<dim3(NCHUNK, NCHAIN), blk, 0, stream>>>(Kf, Vf, KVc, KSc);
    // chunked linear attention
    attn_chunk_kernel<<<dim3(NCHUNK, NCHAIN), blk, 0, stream>>>(Q, Kf, Vf, KVc, KSc, ATT);
    // attn_out = ATT @ Wo
    gemm_kernel<0><<<dim3(8, 64), blk, 0, stream>>>(ATT, 512, Wo, 512, AO, 512, 512);
    // out = LN(h + attn_out)
    ln_kernel<<<dim3(1024), blk, 0, stream>>>(h, AO, gamma, beta, (float*)d_out);
}

// Round 2
// 199.054 us; speedup vs baseline: 2.5093x; 2.5093x over previous
//
#include <hip/hip_runtime.h>
#include <hip/hip_bf16.h>
#include <math.h>

#define S_LEN 2048
#define BATCH 2
#define DMODEL 512
#define NHEAD 8
#define DHEAD 64
#define CHUNK 64
#define NCHUNK 32
#define NCHAIN 16
#define SCALE 0.125f
#define EPS 1e-5f
#define LN_EPS 1e-5f

typedef short short8 __attribute__((ext_vector_type(8)));
typedef float floatx4 __attribute__((ext_vector_type(4)));

__device__ __forceinline__ float elu1(float x) { return x > 0.f ? x + 1.f : __expf(x); }
__device__ __forceinline__ unsigned short f2bf(float f) {
    __hip_bfloat16 b = __float2bfloat16(f);
    return __builtin_bit_cast(unsigned short, b);
}
__device__ __forceinline__ float bf2f(unsigned short u) {
    unsigned int x = ((unsigned int)u) << 16;
    return __builtin_bit_cast(float, x);
}
__device__ __forceinline__ float blo(unsigned int p) {
    return __builtin_bit_cast(float, p << 16);
}
__device__ __forceinline__ float bhi(unsigned int p) {
    return __builtin_bit_cast(float, p & 0xffff0000u);
}
__device__ __forceinline__ void gload_lds16(const void* g, void* lds) {
    __builtin_amdgcn_global_load_lds(
        (const __attribute__((address_space(1))) unsigned int*)g,
        (__attribute__((address_space(3))) unsigned int*)lds, 16, 0, 0);
}

// ---------------- pack: h -> bf16; weights -> transposed bf16 (B^T form) ----
// hB [4096][512]; WqkvT [1536][512] (rows: 0-511 Wq cols, 512-1535 Wkv cols);
// WoT [512][512] = Wo^T
__global__ __launch_bounds__(256)
void pack_kernel(const float* __restrict__ h, const float* __restrict__ Wq,
                 const float* __restrict__ Wkv, const float* __restrict__ Wo,
                 unsigned short* __restrict__ hB, unsigned short* __restrict__ WqkvT,
                 unsigned short* __restrict__ WoT) {
    const int idx = (blockIdx.x * 256 + threadIdx.x) * 4;
    if (idx < 2097152) {
        float4 v = *(const float4*)(h + idx);
        ushort4 o;
        o.x = f2bf(v.x); o.y = f2bf(v.y); o.z = f2bf(v.z); o.w = f2bf(v.w);
        *(ushort4*)(hB + idx) = o;
    } else if (idx < 2883584) {
        int e = idx - 2097152;
        int n = e >> 9, k = e & 511;
        const float* src; int ld, col;
        if (n < 512) { src = Wq; ld = 512; col = n; }
        else         { src = Wkv; ld = 1024; col = n - 512; }
        ushort4 o;
        o.x = f2bf(src[(size_t)(k + 0) * ld + col]);
        o.y = f2bf(src[(size_t)(k + 1) * ld + col]);
        o.z = f2bf(src[(size_t)(k + 2) * ld + col]);
        o.w = f2bf(src[(size_t)(k + 3) * ld + col]);
        *(ushort4*)(WqkvT + e) = o;
    } else if (idx < 3145728) {
        int e = idx - 2883584;
        int n = e >> 9, k = e & 511;
        ushort4 o;
        o.x = f2bf(Wo[(size_t)(k + 0) * 512 + n]);
        o.y = f2bf(Wo[(size_t)(k + 1) * 512 + n]);
        o.z = f2bf(Wo[(size_t)(k + 2) * 512 + n]);
        o.w = f2bf(Wo[(size_t)(k + 3) * 512 + n]);
        *(ushort4*)(WoT + e) = o;
    }
}

// ---------------- bf16 MFMA GEMM: C[M,N] = A[M,K] @ BT[N,K]^T ---------------
// 128x128 tile, BK=32, 4 waves, 16x16x32 mfma, global_load_lds + XOR swizzle.
template <typename OUTT, int ELU_LIM>
__global__ __launch_bounds__(256)
void gemm_mfma(const unsigned short* __restrict__ A,
               const unsigned short* __restrict__ BT,
               OUTT* __restrict__ C, int M, int N, int K) {
    __shared__ __align__(16) unsigned short As[128 * 32];
    __shared__ __align__(16) unsigned short Bs[128 * 32];
    const int tid = threadIdx.x;
    const int w = tid >> 6, l = tid & 63;
    const int m0 = blockIdx.y * 128, n0 = blockIdx.x * 128;
    const int wm = (w >> 1) * 64, wn = (w & 1) * 64;
    floatx4 acc[4][4];
#pragma unroll
    for (int i = 0; i < 4; ++i)
#pragma unroll
        for (int j = 0; j < 4; ++j)
#pragma unroll
            for (int e = 0; e < 4; ++e) acc[i][j][e] = 0.f;

    for (int kt = 0; kt < K; kt += 32) {
        __syncthreads();
#pragma unroll
        for (int r = 0; r < 2; ++r) {
            int slot = (r * 4 + w) * 64 + l;
            int row = slot >> 2, part = slot & 3;
            int g = part ^ (row & 3);  // pre-swizzled global source (m173 pattern)
            gload_lds16(A + (size_t)(m0 + row) * K + kt + g * 8,
                        As + (r * 4 + w) * 512);
            gload_lds16(BT + (size_t)(n0 + row) * K + kt + g * 8,
                        Bs + (r * 4 + w) * 512);
        }
        __syncthreads();
        short8 a[4], b[4];
#pragma unroll
        for (int mi = 0; mi < 4; ++mi) {
            int row = wm + mi * 16 + (l & 15);
            int p = (l >> 4) ^ (row & 3);
            a[mi] = *(const short8*)(As + row * 32 + p * 8);
        }
#pragma unroll
        for (int ni = 0; ni < 4; ++ni) {
            int row = wn + ni * 16 + (l & 15);
            int p = (l >> 4) ^ (row & 3);
            b[ni] = *(const short8*)(Bs + row * 32 + p * 8);
        }
#pragma unroll
        for (int mi = 0; mi < 4; ++mi)
#pragma unroll
            for (int ni = 0; ni < 4; ++ni)
                acc[mi][ni] = __builtin_amdgcn_mfma_f32_16x16x32_bf16(
                    a[mi], b[ni], acc[mi][ni], 0, 0, 0);
    }
#pragma unroll
    for (int mi = 0; mi < 4; ++mi)
#pragma unroll
        for (int ni = 0; ni < 4; ++ni)
#pragma unroll
            for (int r = 0; r < 4; ++r) {
                int row = m0 + wm + mi * 16 + (l >> 4) * 4 + r;
                int col = n0 + wn + ni * 16 + (l & 15);
                float v = acc[mi][ni][r];
                if (col < ELU_LIM) v = elu1(v);
                if constexpr (sizeof(OUTT) == 2)
                    C[(size_t)row * N + col] = (OUTT)f2bf(v);
                else
                    C[(size_t)row * N + col] = (OUTT)v;
            }
}

// ---------------- per-chunk KV outer product + K sums ----------------------
__global__ __launch_bounds__(256)
void chunk_kv_kernel(const unsigned short* __restrict__ QKVb,
                     float* __restrict__ KVc, float* __restrict__ KSc) {
    __shared__ __align__(16) unsigned short Kl[64][64];
    __shared__ __align__(16) unsigned short Vl[64][64];
    const int c = blockIdx.x, chain = blockIdx.y;
    const int b = chain >> 3, hh = chain & 7;
    const int tid = threadIdx.x;
#pragma unroll
    for (int r = 0; r < 2; ++r) {
        int slot = r * 256 + tid;
        int j = slot >> 3, part = slot & 7;
        size_t grow = ((size_t)(c * 64 + j) * BATCH + b) * 1536;
        *(uint4*)&Kl[j][part * 8] = *(const uint4*)(QKVb + grow + 512 + hh * 64 + part * 8);
        *(uint4*)&Vl[j][part * 8] = *(const uint4*)(QKVb + grow + 1024 + hh * 64 + part * 8);
    }
    __syncthreads();
    const int w = tid >> 6, l = tid & 63;
    float* out = KVc + (size_t)(chain * NCHUNK + c) * 4096;
#pragma unroll 1
    for (int t = 0; t < 16; ++t) {
        int dk = t * 4 + w;  // wave-uniform -> broadcast Kl reads
        float acc = 0.f;
#pragma unroll 8
        for (int j = 0; j < 64; ++j)
            acc = fmaf(bf2f(Kl[j][dk]), bf2f(Vl[j][l]), acc);
        out[dk * 64 + l] = acc;
    }
    if (tid < 64) {
        float s = 0.f;
#pragma unroll 8
        for (int j = 0; j < 64; ++j) s += bf2f(Kl[j][tid]);
        KSc[(size_t)(chain * NCHUNK + c) * 64 + tid] = s;
    }
}

// ---------------- exclusive prefix-sum of KV states over chunks ------------
__global__ __launch_bounds__(256)
void cumsum_kernel(const float* __restrict__ KVc, const float* __restrict__ KSc,
                   float* __restrict__ KVcum, float* __restrict__ KScum) {
    const int chain = blockIdx.x, part = blockIdx.y;
    const int tid = threadIdx.x;
    const size_t base = (size_t)chain * NCHUNK * 4096;
    const int off = part * 1024 + tid * 4;
    float4 acc = make_float4(0.f, 0.f, 0.f, 0.f);
    for (int cc = 0; cc < NCHUNK; ++cc) {
        *(float4*)(KVcum + base + cc * 4096 + off) = acc;  // exclusive
        float4 v = *(const float4*)(KVc + base + cc * 4096 + off);
        acc.x += v.x; acc.y += v.y; acc.z += v.z; acc.w += v.w;
    }
    if (part == 0 && tid < 64) {
        float s = 0.f;
        for (int cc = 0; cc < NCHUNK; ++cc) {
            KScum[(size_t)(chain * NCHUNK + cc) * 64 + tid] = s;
            s += KSc[(size_t)(chain * NCHUNK + cc) * 64 + tid];
        }
    }
}

// ---------------- chunked linear attention (no serial prefix) --------------
__global__ __launch_bounds__(256)
void attn_chunk_kernel(const unsigned short* __restrict__ QKVb,
                       const float* __restrict__ KVcum,
                       const float* __restrict__ KScum,
                       unsigned short* __restrict__ ATT) {
    __shared__ __align__(16) unsigned short Qlb[64][64];
    __shared__ __align__(16) unsigned short Vlb[64][64];
    __shared__ __align__(16) float Mp[64][64];
    __shared__ __align__(16) float Sc[64][64];
    __shared__ float Sprev[64];
    const int c = blockIdx.x, chain = blockIdx.y;
    const int b = chain >> 3, hh = chain & 7;
    const int tid = threadIdx.x;
    const int w = tid >> 6, l = tid & 63;
    const size_t mbase = (size_t)(chain * NCHUNK + c) * 4096;

    // stage Q, V (bf16) via global_load_lds: per wave-instr 8 rows x 128B
#pragma unroll
    for (int r = 0; r < 2; ++r) {
        int jbase = (r * 4 + w) * 8;
        int j = jbase + (l >> 3), part = l & 7;
        size_t grow = ((size_t)(c * 64 + j) * BATCH + b) * 1536;
        gload_lds16(QKVb + grow + hh * 64 + part * 8, &Qlb[jbase][0]);
        gload_lds16(QKVb + grow + 1024 + hh * 64 + part * 8, &Vlb[jbase][0]);
    }
    // stage prefix state Mp (fp32, 16KB): per wave-instr 4 rows x 1KB
#pragma unroll
    for (int r = 0; r < 4; ++r) {
        int slot = r * 4 + w;
        gload_lds16(KVcum + mbase + slot * 256 + l * 4, &Mp[slot * 4][0]);
    }
    if (w == 0) Sprev[l] = KScum[(size_t)(chain * NCHUNK + c) * 64 + l];

    // K row (row = lane) into registers, packed bf16x2
    unsigned int kp[32];
    {
        const uint4* ks = (const uint4*)(QKVb + ((size_t)(c * 64 + l) * BATCH + b) * 1536 + 512 + hh * 64);
#pragma unroll
        for (int q = 0; q < 8; ++q) {
            uint4 v = ks[q];
            kp[q * 4 + 0] = v.x; kp[q * 4 + 1] = v.y;
            kp[q * 4 + 2] = v.z; kp[q * 4 + 3] = v.w;
        }
    }
    __syncthreads();

    // intra-chunk causal scores: S[i][j=lane] = q_i . k_lane  (j <= i)
#pragma unroll 1
    for (int t = 0; t < 16; ++t) {
        int i = t * 4 + w;  // wave-uniform
        float s = 0.f;
        if (l <= i) {
            const unsigned int* qrow = (const unsigned int*)&Qlb[i][0];  // broadcast
#pragma unroll
            for (int dp = 0; dp < 32; ++dp) {
                unsigned int q2 = qrow[dp], k2 = kp[dp];
                s = fmaf(blo(q2), blo(k2), fmaf(bhi(q2), bhi(k2), s));
            }
        }
        Sc[i][l] = s;
    }
    __syncthreads();

    // combine intra (S@V) + inter (Q@Mp) and normalize
#pragma unroll 1
    for (int t = 0; t < 16; ++t) {
        int i = t * 4 + w;
        float num = 0.f, den = 0.f;
#pragma unroll 8
        for (int j = 0; j < 64; ++j) {
            float wgt = Sc[i][j];  // broadcast
            num = fmaf(wgt, bf2f(Vlb[j][l]), num);
            den += wgt;
        }
        float num2 = 0.f, den2 = 0.f;
        const unsigned int* qrow = (const unsigned int*)&Qlb[i][0];
#pragma unroll 8
        for (int dp = 0; dp < 32; ++dp) {
            unsigned int q2 = qrow[dp];
            float q0 = blo(q2), q1 = bhi(q2);
            num2 = fmaf(q0, Mp[2 * dp][l], fmaf(q1, Mp[2 * dp + 1][l], num2));
            den2 = fmaf(q0, Sprev[2 * dp], fmaf(q1, Sprev[2 * dp + 1], den2));
        }
        float denom = SCALE * (den + den2) + EPS;
        float o = SCALE * (num + num2) / denom;
        ATT[((size_t)(c * 64 + i) * BATCH + b) * DMODEL + hh * 64 + l] = f2bf(o);
    }
}

// ---------------- fused residual + LayerNorm (wave per row) ----------------
__global__ __launch_bounds__(256)
void ln_kernel(const float* __restrict__ h, const float* __restrict__ AO,
               const float* __restrict__ gamma, const float* __restrict__ beta,
               float* __restrict__ out) {
    const int tid = threadIdx.x;
    const int lane = tid & 63, wave = tid >> 6;
    const int row = blockIdx.x * 4 + wave;
    float v[8];
    float sum = 0.f;
#pragma unroll
    for (int i = 0; i < 8; ++i) {
        int col = lane + i * 64;
        float x = h[(size_t)row * DMODEL + col] + AO[(size_t)row * DMODEL + col];
        v[i] = x;
        sum += x;
    }
#pragma unroll
    for (int off = 32; off >= 1; off >>= 1) sum += __shfl_xor(sum, off, 64);
    float mean = sum * (1.f / DMODEL);
    float var = 0.f;
#pragma unroll
    for (int i = 0; i < 8; ++i) {
        float d = v[i] - mean;
        var = fmaf(d, d, var);
    }
#pragma unroll
    for (int off = 32; off >= 1; off >>= 1) var += __shfl_xor(var, off, 64);
    float rstd = rsqrtf(var * (1.f / DMODEL) + LN_EPS);
#pragma unroll
    for (int i = 0; i < 8; ++i) {
        int col = lane + i * 64;
        out[(size_t)row * DMODEL + col] = (v[i] - mean) * rstd * gamma[col] + beta[col];
    }
}

extern "C" void kernel_launch(void* const* d_in, const int* in_sizes, int n_in,
                              void* d_out, int out_size, void* d_ws, size_t ws_size,
                              hipStream_t stream) {
    const float* h = (const float*)d_in[0];
    const float* Wq = (const float*)d_in[1];
    const float* Wkv = (const float*)d_in[2];
    const float* Wo = (const float*)d_in[3];
    const float* gamma = (const float*)d_in[4];
    const float* beta = (const float*)d_in[5];

    char* ws = (char*)d_ws;
    unsigned short* hB    = (unsigned short*)ws;               //  4.0 MB [4096][512]
    unsigned short* WqkvT = (unsigned short*)(ws + 4194304);   //  1.5 MB [1536][512]
    unsigned short* WoT   = (unsigned short*)(ws + 5767168);   //  0.5 MB [512][512]
    unsigned short* QKVb  = (unsigned short*)(ws + 6291456);   // 12.0 MB [4096][1536]
    unsigned short* ATT   = (unsigned short*)(ws + 18874368);  //  4.0 MB [4096][512]
    float*          KVc   = (float*)(ws + 23068672);           //  8.0 MB
    float*          KVcum = (float*)(ws + 31457280);           //  8.0 MB
    float*          KSc   = (float*)(ws + 39845888);           //  128 KB
    float*          KScum = (float*)(ws + 39976960);           //  128 KB
    float*          AO    = (float*)QKVb;                      //  8.0 MB (QKVb dead after attn)

    dim3 blk(256);
    pack_kernel<<<3072, blk, 0, stream>>>(h, Wq, Wkv, Wo, hB, WqkvT, WoT);
    gemm_mfma<unsigned short, 1024><<<dim3(12, 32), blk, 0, stream>>>(hB, WqkvT, QKVb, 4096, 1536, 512);
    chunk_kv_kernel<<<dim3(NCHUNK, NCHAIN), blk, 0, stream>>>(QKVb, KVc, KSc);
    cumsum_kernel<<<dim3(NCHAIN, 4), blk, 0, stream>>>(KVc, KSc, KVcum, KScum);
    attn_chunk_kernel<<<dim3(NCHUNK, NCHAIN), blk, 0, stream>>>(QKVb, KVcum, KScum, ATT);
    gemm_mfma<float, 0><<<dim3(4, 32), blk, 0, stream>>>(ATT, WoT, AO, 4096, 512, 512);
    ln_kernel<<<1024, blk, 0, stream>>>(h, AO, gamma, beta, (float*)d_out);
}

// Round 3
// 147.107 us; speedup vs baseline: 3.3955x; 1.3531x over previous
//
#include <hip/hip_runtime.h>
#include <hip/hip_bf16.h>
#include <math.h>

#define SCALE 0.125f
#define EPS 1e-5f
#define LN_EPS 1e-5f

typedef short short8 __attribute__((ext_vector_type(8)));
typedef float floatx4 __attribute__((ext_vector_type(4)));
typedef unsigned short us;

__device__ __forceinline__ float elu1(float x) { return x > 0.f ? x + 1.f : __expf(x); }
__device__ __forceinline__ us f2bf(float f) {
    __hip_bfloat16 b = __float2bfloat16(f);
    return __builtin_bit_cast(us, b);
}
__device__ __forceinline__ void gload_lds16(const void* g, void* lds) {
    __builtin_amdgcn_global_load_lds(
        (const __attribute__((address_space(1))) unsigned int*)g,
        (__attribute__((address_space(3))) unsigned int*)lds, 16, 0, 0);
}
__device__ __forceinline__ floatx4 mfma_bf16(short8 a, short8 b, floatx4 c) {
    return __builtin_amdgcn_mfma_f32_16x16x32_bf16(a, b, c, 0, 0, 0);
}

// ---------------- pack: h->bf16, W->B^T bf16, VTg ones row ------------------
__global__ __launch_bounds__(256)
void pack_kernel(const float* __restrict__ h, const float* __restrict__ Wq,
                 const float* __restrict__ Wkv, const float* __restrict__ Wo,
                 us* __restrict__ hB, us* __restrict__ WqkvT, us* __restrict__ WoT,
                 us* __restrict__ VTg) {
    const int idx = (blockIdx.x * 256 + threadIdx.x) * 4;
    if (idx < 2097152) {
        float4 v = *(const float4*)(h + idx);
        ushort4 o;
        o.x = f2bf(v.x); o.y = f2bf(v.y); o.z = f2bf(v.z); o.w = f2bf(v.w);
        *(ushort4*)(hB + idx) = o;
    } else if (idx < 2883584) {
        int e = idx - 2097152;
        int n = e >> 9, k = e & 511;
        const float* src; int ld, col;
        if (n < 512) { src = Wq; ld = 512; col = n; }
        else         { src = Wkv; ld = 1024; col = n - 512; }
        ushort4 o;
        o.x = f2bf(src[(size_t)(k + 0) * ld + col]);
        o.y = f2bf(src[(size_t)(k + 1) * ld + col]);
        o.z = f2bf(src[(size_t)(k + 2) * ld + col]);
        o.w = f2bf(src[(size_t)(k + 3) * ld + col]);
        *(ushort4*)(WqkvT + e) = o;
    } else if (idx < 3145728) {
        int e = idx - 2883584;
        int n = e >> 9, k = e & 511;
        ushort4 o;
        o.x = f2bf(Wo[(size_t)(k + 0) * 512 + n]);
        o.y = f2bf(Wo[(size_t)(k + 1) * 512 + n]);
        o.z = f2bf(Wo[(size_t)(k + 2) * 512 + n]);
        o.w = f2bf(Wo[(size_t)(k + 3) * 512 + n]);
        *(ushort4*)(WoT + e) = o;
    } else if (idx < 3178496) {
        int e = idx - 3145728;
        int chain = e >> 11, s = e & 2047;
        ushort4 o; o.x = 0x3f80; o.y = 0x3f80; o.z = 0x3f80; o.w = 0x3f80;
        *(ushort4*)(VTg + ((size_t)(chain * 80 + 64)) * 2048 + s) = o;
    }
}

// ---------------- QKV GEMM: [4096,512]@[512,1536] -> Qg/Kg/Vg (elu on Q,K) --
__global__ __launch_bounds__(256)
void qkv_gemm(const us* __restrict__ A, const us* __restrict__ BT,
              us* __restrict__ Qg, us* __restrict__ Kg, us* __restrict__ Vg) {
    __shared__ __align__(16) us As[128 * 32];
    __shared__ __align__(16) us Bs[128 * 32];
    const int tid = threadIdx.x;
    const int w = tid >> 6, l = tid & 63;
    const int m0 = blockIdx.y * 128, n0 = blockIdx.x * 128;
    const int wm = (w >> 1) * 64, wn = (w & 1) * 64;
    floatx4 acc[4][4];
#pragma unroll
    for (int i = 0; i < 4; ++i)
#pragma unroll
        for (int j = 0; j < 4; ++j)
#pragma unroll
            for (int e = 0; e < 4; ++e) acc[i][j][e] = 0.f;

    for (int kt = 0; kt < 512; kt += 32) {
        __syncthreads();
#pragma unroll
        for (int r = 0; r < 2; ++r) {
            int slot = (r * 4 + w) * 64 + l;
            int row = slot >> 2, part = slot & 3;
            int g = part ^ (row & 3);
            gload_lds16(A + (size_t)(m0 + row) * 512 + kt + g * 8, As + (r * 4 + w) * 512);
            gload_lds16(BT + (size_t)(n0 + row) * 512 + kt + g * 8, Bs + (r * 4 + w) * 512);
        }
        __syncthreads();
        short8 a[4], b[4];
#pragma unroll
        for (int mi = 0; mi < 4; ++mi) {
            int row = wm + mi * 16 + (l & 15);
            int p = (l >> 4) ^ (row & 3);
            a[mi] = *(const short8*)(As + row * 32 + p * 8);
        }
#pragma unroll
        for (int ni = 0; ni < 4; ++ni) {
            int row = wn + ni * 16 + (l & 15);
            int p = (l >> 4) ^ (row & 3);
            b[ni] = *(const short8*)(Bs + row * 32 + p * 8);
        }
#pragma unroll
        for (int mi = 0; mi < 4; ++mi)
#pragma unroll
            for (int ni = 0; ni < 4; ++ni)
                acc[mi][ni] = mfma_bf16(a[mi], b[ni], acc[mi][ni]);
    }
    const int region = blockIdx.x >> 2;  // 0=Q 1=K 2=V (128 | 512)
    us* outp = region == 0 ? Qg : (region == 1 ? Kg : Vg);
    const int cb = n0 - region * 512;
#pragma unroll
    for (int mi = 0; mi < 4; ++mi)
#pragma unroll
        for (int ni = 0; ni < 4; ++ni)
#pragma unroll
            for (int r = 0; r < 4; ++r) {
                int row = m0 + wm + mi * 16 + (l >> 4) * 4 + r;
                int col = cb + wn + ni * 16 + (l & 15);
                float v = acc[mi][ni][r];
                if (region < 2) v = elu1(v);
                outp[(size_t)row * 512 + col] = f2bf(v);
            }
}

// ---------------- per-chunk: C[dv][dk] = V^T K^T-form + ksum row; mirror VTg -
__global__ __launch_bounds__(256)
void chunk_kv_kernel(const us* __restrict__ Kg, const us* __restrict__ Vg,
                     float* __restrict__ KVc, us* __restrict__ VTg) {
    __shared__ __align__(16) us VT_l[80 * 72];
    __shared__ __align__(16) us KT_l[64 * 72];
    const int c = blockIdx.x, chain = blockIdx.y;
    const int b = chain >> 3, hh = chain & 7;
    const int tid = threadIdx.x;
    const int w = tid >> 6, l = tid & 63;
#pragma unroll
    for (int gi = 0; gi < 2; ++gi) {
        int g = w + gi * 4;
        __align__(16) us vv[8];
        __align__(16) us kk[8];
#pragma unroll
        for (int e = 0; e < 8; ++e) {
            size_t off = (size_t)((c * 64 + g * 8 + e) * 2 + b) * 512 + hh * 64 + l;
            vv[e] = Vg[off];
            kk[e] = Kg[off];
        }
        *(uint4*)(VT_l + l * 72 + g * 8) = *(uint4*)vv;
        *(uint4*)(KT_l + l * 72 + g * 8) = *(uint4*)kk;
        *(uint4*)(VTg + ((size_t)(chain * 80 + l)) * 2048 + c * 64 + g * 8) = *(uint4*)vv;
    }
    if (tid < 8) {
        ushort4 o; o.x = 0x3f80; o.y = 0x3f80; o.z = 0x3f80; o.w = 0x3f80;
        *(ushort4*)(VT_l + 64 * 72 + tid * 8) = o;
        *(ushort4*)(VT_l + 64 * 72 + tid * 8 + 4) = o;
    }
    __syncthreads();
    const int l15 = l & 15, l4 = l >> 4;
    short8 af[5][2], bfr[2];
#pragma unroll
    for (int mi = 0; mi < 5; ++mi) {
        int row = mi * 16 + l15;
        af[mi][0] = *(const short8*)(VT_l + row * 72 + l4 * 8);
        af[mi][1] = *(const short8*)(VT_l + row * 72 + 32 + l4 * 8);
    }
    {
        int row = w * 16 + l15;
        bfr[0] = *(const short8*)(KT_l + row * 72 + l4 * 8);
        bfr[1] = *(const short8*)(KT_l + row * 72 + 32 + l4 * 8);
    }
    float* out = KVc + (size_t)(chain * 32 + c) * 4608;
#pragma unroll
    for (int mi = 0; mi < 5; ++mi) {
        floatx4 a = {0.f, 0.f, 0.f, 0.f};
        a = mfma_bf16(af[mi][0], bfr[0], a);
        a = mfma_bf16(af[mi][1], bfr[1], a);
#pragma unroll
        for (int r = 0; r < 4; ++r) {
            int row = mi * 16 + l4 * 4 + r;
            if (row < 65) out[row * 64 + w * 16 + l15] = a[r];
        }
    }
}

// ---------------- exclusive prefix over chunks -> bf16 MTg -----------------
__global__ __launch_bounds__(256)
void cumsum_kernel(const float* __restrict__ KVc, us* __restrict__ MTg) {
    const int chain = blockIdx.x, rg = blockIdx.y;
    const int row = rg * 4 + (threadIdx.x >> 6), col = threadIdx.x & 63;
    const float* in = KVc + (size_t)chain * 32 * 4608 + row * 64 + col;
    us* out = MTg + ((size_t)chain * 32 * 80 + row) * 64 + col;
    float acc = 0.f;
#pragma unroll 4
    for (int cc = 0; cc < 32; ++cc) {
        out[(size_t)cc * 5120] = f2bf(acc);
        acc += in[(size_t)cc * 4608];
    }
}

// ---------------- MFMA attention per (chunk, chain) ------------------------
__global__ __launch_bounds__(256)
void attn_kernel(const us* __restrict__ Qg, const us* __restrict__ Kg,
                 const us* __restrict__ VTg, const us* __restrict__ MTg,
                 us* __restrict__ ATT) {
    __shared__ __align__(16) us Sl[64 * 64];
    const int c = blockIdx.x, chain = blockIdx.y;
    const int b = chain >> 3, hh = chain & 7;
    const int tid = threadIdx.x;
    const int w = tid >> 6, l = tid & 63;
    const int l15 = l & 15, l4 = l >> 4;

    short8 qf[2];
    {
        const us* qb = Qg + ((size_t)((c * 64 + w * 16 + l15) * 2 + b)) * 512 + hh * 64 + l4 * 8;
        qf[0] = *(const short8*)(qb);
        qf[1] = *(const short8*)(qb + 32);
    }
    short8 kf[4][2];
#pragma unroll
    for (int ni = 0; ni < 4; ++ni) {
        const us* kb = Kg + ((size_t)((c * 64 + ni * 16 + l15) * 2 + b)) * 512 + hh * 64 + l4 * 8;
        kf[ni][0] = *(const short8*)(kb);
        kf[ni][1] = *(const short8*)(kb + 32);
    }
    short8 vf[5][2];
#pragma unroll
    for (int ni = 0; ni < 5; ++ni) {
        const us* vb = VTg + ((size_t)(chain * 80 + ni * 16 + l15)) * 2048 + c * 64 + l4 * 8;
        vf[ni][0] = *(const short8*)(vb);
        vf[ni][1] = *(const short8*)(vb + 32);
    }
    short8 mf[5][2];
#pragma unroll
    for (int ni = 0; ni < 5; ++ni) {
        const us* mb = MTg + ((size_t)((chain * 32 + c) * 80 + ni * 16 + l15)) * 64 + l4 * 8;
        mf[ni][0] = *(const short8*)(mb);
        mf[ni][1] = *(const short8*)(mb + 32);
    }

    // phase 1: S = Q @ K^T (raw), causal mask, -> bf16 Sl (XOR-swizzled parts)
    const int ibase = w * 16 + l4 * 4;
#pragma unroll
    for (int ni = 0; ni < 4; ++ni) {
        floatx4 s = {0.f, 0.f, 0.f, 0.f};
        s = mfma_bf16(qf[0], kf[ni][0], s);
        s = mfma_bf16(qf[1], kf[ni][1], s);
        int col = ni * 16 + l15;
#pragma unroll
        for (int r = 0; r < 4; ++r) {
            int i = ibase + r;
            float v = (col <= i) ? s[r] : 0.f;
            Sl[i * 64 + (((col >> 3) ^ (i & 7)) * 8) + (col & 7)] = f2bf(v);
        }
    }
    __syncthreads();

    short8 sf[2];
    {
        int ir = w * 16 + l15;
        sf[0] = *(const short8*)(Sl + ir * 64 + ((l4 ^ (ir & 7)) * 8));
        sf[1] = *(const short8*)(Sl + ir * 64 + (((4 + l4) ^ (ir & 7)) * 8));
    }

    // phases 2+3: acc = S@V_ext + Q@MpT_ext ; col 64 = raw denominator
    floatx4 acc[5];
#pragma unroll
    for (int ni = 0; ni < 5; ++ni) {
        floatx4 a = {0.f, 0.f, 0.f, 0.f};
        a = mfma_bf16(sf[0], vf[ni][0], a);
        a = mfma_bf16(sf[1], vf[ni][1], a);
        a = mfma_bf16(qf[0], mf[ni][0], a);
        a = mfma_bf16(qf[1], mf[ni][1], a);
        acc[ni] = a;
    }

    float fac[4];
#pragma unroll
    for (int r = 0; r < 4; ++r) {
        float den = __shfl(acc[4][r], l & 48, 64);
        fac[r] = SCALE / (SCALE * den + EPS);
    }
#pragma unroll
    for (int ni = 0; ni < 4; ++ni)
#pragma unroll
        for (int r = 0; r < 4; ++r) {
            int i = ibase + r;
            ATT[((size_t)((c * 64 + i) * 2 + b)) * 512 + hh * 64 + ni * 16 + l15] =
                f2bf(acc[ni][r] * fac[r]);
        }
}

// ---------------- generic bf16 GEMM (Wo): C = A @ BT^T ---------------------
template <typename OUTT, int ELU_LIM>
__global__ __launch_bounds__(256)
void gemm_mfma(const us* __restrict__ A, const us* __restrict__ BT,
               OUTT* __restrict__ C, int M, int N, int K) {
    __shared__ __align__(16) us As[128 * 32];
    __shared__ __align__(16) us Bs[128 * 32];
    const int tid = threadIdx.x;
    const int w = tid >> 6, l = tid & 63;
    const int m0 = blockIdx.y * 128, n0 = blockIdx.x * 128;
    const int wm = (w >> 1) * 64, wn = (w & 1) * 64;
    floatx4 acc[4][4];
#pragma unroll
    for (int i = 0; i < 4; ++i)
#pragma unroll
        for (int j = 0; j < 4; ++j)
#pragma unroll
            for (int e = 0; e < 4; ++e) acc[i][j][e] = 0.f;
    for (int kt = 0; kt < K; kt += 32) {
        __syncthreads();
#pragma unroll
        for (int r = 0; r < 2; ++r) {
            int slot = (r * 4 + w) * 64 + l;
            int row = slot >> 2, part = slot & 3;
            int g = part ^ (row & 3);
            gload_lds16(A + (size_t)(m0 + row) * K + kt + g * 8, As + (r * 4 + w) * 512);
            gload_lds16(BT + (size_t)(n0 + row) * K + kt + g * 8, Bs + (r * 4 + w) * 512);
        }
        __syncthreads();
        short8 a[4], b[4];
#pragma unroll
        for (int mi = 0; mi < 4; ++mi) {
            int row = wm + mi * 16 + (l & 15);
            int p = (l >> 4) ^ (row & 3);
            a[mi] = *(const short8*)(As + row * 32 + p * 8);
        }
#pragma unroll
        for (int ni = 0; ni < 4; ++ni) {
            int row = wn + ni * 16 + (l & 15);
            int p = (l >> 4) ^ (row & 3);
            b[ni] = *(const short8*)(Bs + row * 32 + p * 8);
        }
#pragma unroll
        for (int mi = 0; mi < 4; ++mi)
#pragma unroll
            for (int ni = 0; ni < 4; ++ni)
                acc[mi][ni] = mfma_bf16(a[mi], b[ni], acc[mi][ni]);
    }
#pragma unroll
    for (int mi = 0; mi < 4; ++mi)
#pragma unroll
        for (int ni = 0; ni < 4; ++ni)
#pragma unroll
            for (int r = 0; r < 4; ++r) {
                int row = m0 + wm + mi * 16 + (l >> 4) * 4 + r;
                int col = n0 + wn + ni * 16 + (l & 15);
                float v = acc[mi][ni][r];
                if (col < ELU_LIM) v = elu1(v);
                if constexpr (sizeof(OUTT) == 2)
                    C[(size_t)row * N + col] = (OUTT)f2bf(v);
                else
                    C[(size_t)row * N + col] = (OUTT)v;
            }
}

// ---------------- fused residual + LayerNorm -------------------------------
__global__ __launch_bounds__(256)
void ln_kernel(const float* __restrict__ h, const float* __restrict__ AO,
               const float* __restrict__ gamma, const float* __restrict__ beta,
               float* __restrict__ out) {
    const int tid = threadIdx.x;
    const int lane = tid & 63, wave = tid >> 6;
    const int row = blockIdx.x * 4 + wave;
    float v[8];
    float sum = 0.f;
#pragma unroll
    for (int i = 0; i < 8; ++i) {
        int col = lane + i * 64;
        float x = h[(size_t)row * 512 + col] + AO[(size_t)row * 512 + col];
        v[i] = x;
        sum += x;
    }
#pragma unroll
    for (int off = 32; off >= 1; off >>= 1) sum += __shfl_xor(sum, off, 64);
    float mean = sum * (1.f / 512);
    float var = 0.f;
#pragma unroll
    for (int i = 0; i < 8; ++i) {
        float d = v[i] - mean;
        var = fmaf(d, d, var);
    }
#pragma unroll
    for (int off = 32; off >= 1; off >>= 1) var += __shfl_xor(var, off, 64);
    float rstd = rsqrtf(var * (1.f / 512) + LN_EPS);
#pragma unroll
    for (int i = 0; i < 8; ++i) {
        int col = lane + i * 64;
        out[(size_t)row * 512 + col] = (v[i] - mean) * rstd * gamma[col] + beta[col];
    }
}

extern "C" void kernel_launch(void* const* d_in, const int* in_sizes, int n_in,
                              void* d_out, int out_size, void* d_ws, size_t ws_size,
                              hipStream_t stream) {
    const float* h = (const float*)d_in[0];
    const float* Wq = (const float*)d_in[1];
    const float* Wkv = (const float*)d_in[2];
    const float* Wo = (const float*)d_in[3];
    const float* gamma = (const float*)d_in[4];
    const float* beta = (const float*)d_in[5];

    char* ws = (char*)d_ws;
    us* Qg      = (us*)(ws + 0);          //  4 MB [4096][512]
    us* Kg      = (us*)(ws + 4194304);    //  4 MB
    us* Vg      = (us*)(ws + 8388608);    //  4 MB
    us* VTg     = (us*)(ws + 12582912);   //  5.25 MB [16][80][2048]
    us* ATT     = (us*)(ws + 17825792);   //  4 MB
    us* WoT     = (us*)(ws + 22020096);   //  0.5 MB
    us* MTg     = (us*)(ws + 22544384);   //  5.25 MB [16][32][80][64]
    us* hB      = (us*)(ws + 27787264);   //  4 MB (dead after qkv_gemm)
    us* WqkvT   = (us*)(ws + 31981568);   //  1.5 MB (dead after qkv_gemm)
    float* KVc  = (float*)(ws + 27787264);//  9.44 MB (overlaps hB/WqkvT, after)
    float* AO   = (float*)(ws + 0);       //  8 MB (overlaps Qg/Kg, after attn)

    dim3 blk(256);
    pack_kernel<<<3104, blk, 0, stream>>>(h, Wq, Wkv, Wo, hB, WqkvT, WoT, VTg);
    qkv_gemm<<<dim3(12, 32), blk, 0, stream>>>(hB, WqkvT, Qg, Kg, Vg);
    chunk_kv_kernel<<<dim3(32, 16), blk, 0, stream>>>(Kg, Vg, KVc, VTg);
    cumsum_kernel<<<dim3(16, 17), blk, 0, stream>>>(KVc, MTg);
    attn_kernel<<<dim3(32, 16), blk, 0, stream>>>(Qg, Kg, VTg, MTg, ATT);
    gemm_mfma<float, 0><<<dim3(4, 32), blk, 0, stream>>>(ATT, WoT, AO, 4096, 512, 512);
    ln_kernel<<<1024, blk, 0, stream>>>(h, AO, gamma, beta, (float*)d_out);
}

// Round 4
// 139.053 us; speedup vs baseline: 3.5921x; 1.0579x over previous
//
#include <hip/hip_runtime.h>
#include <hip/hip_bf16.h>
#include <math.h>

#define SCALE 0.125f
#define EPS 1e-5f
#define LN_EPS 1e-5f

typedef short short8 __attribute__((ext_vector_type(8)));
typedef float floatx4 __attribute__((ext_vector_type(4)));
typedef unsigned short us;

__device__ __forceinline__ float elu1(float x) { return x > 0.f ? x + 1.f : __expf(x); }
__device__ __forceinline__ us f2bf(float f) {
    __hip_bfloat16 b = __float2bfloat16(f);
    return __builtin_bit_cast(us, b);
}
__device__ __forceinline__ void gload_lds16(const void* g, void* lds) {
    __builtin_amdgcn_global_load_lds(
        (const __attribute__((address_space(1))) unsigned int*)g,
        (__attribute__((address_space(3))) unsigned int*)lds, 16, 0, 0);
}
__device__ __forceinline__ floatx4 mfma_bf16(short8 a, short8 b, floatx4 c) {
    return __builtin_amdgcn_mfma_f32_16x16x32_bf16(a, b, c, 0, 0, 0);
}

// ---------------- pack: h->bf16 (coalesced), LDS-tiled weight transposes ----
// blocks 0..2047: h; 2048..2239: Wqkv tiles; 2240..2303: Wo tiles; 2304..2335: ones
__global__ __launch_bounds__(256)
void pack_kernel(const float* __restrict__ h, const float* __restrict__ Wq,
                 const float* __restrict__ Wkv, const float* __restrict__ Wo,
                 us* __restrict__ hB, us* __restrict__ WqkvT, us* __restrict__ WoT,
                 us* __restrict__ VTg) {
    const int bid = blockIdx.x, tid = threadIdx.x;
    if (bid < 2048) {
        int idx = bid * 1024 + tid * 4;
        float4 v = *(const float4*)(h + idx);
        ushort4 o;
        o.x = f2bf(v.x); o.y = f2bf(v.y); o.z = f2bf(v.z); o.w = f2bf(v.w);
        *(ushort4*)(hB + idx) = o;
        return;
    }
    if (bid < 2304) {
        __shared__ us T[64][72];
        const float* src; int ld, n0s, k0; us* dst;
        if (bid < 2240) {
            int t2 = bid - 2048;           // Wqkv: 24 n-tiles x 8 k-tiles
            int nt = t2 % 24, kt = t2 / 24;
            int n0 = nt * 64; k0 = kt * 64;
            if (n0 < 512) { src = Wq; ld = 512; n0s = n0; }
            else          { src = Wkv; ld = 1024; n0s = n0 - 512; }
            dst = WqkvT + (size_t)n0 * 512;
        } else {
            int t2 = bid - 2240;           // Wo: 8 x 8
            int nt = t2 & 7, kt = t2 >> 3;
            src = Wo; ld = 512; n0s = nt * 64; k0 = kt * 64;
            dst = WoT + (size_t)(nt * 64) * 512;
        }
        {   // coalesced load: thread t -> row k=t>>2, 16 cols at (t&3)*16
            int k = tid >> 2, cs = (tid & 3) * 16;
            const float* p = src + (size_t)(k0 + k) * ld + n0s + cs;
#pragma unroll
            for (int q = 0; q < 4; ++q) {
                float4 v = *(const float4*)(p + q * 4);
                T[k][cs + q * 4 + 0] = f2bf(v.x);
                T[k][cs + q * 4 + 1] = f2bf(v.y);
                T[k][cs + q * 4 + 2] = f2bf(v.z);
                T[k][cs + q * 4 + 3] = f2bf(v.w);
            }
        }
        __syncthreads();
        {   // transposed write: thread t -> col n=t>>2, 16 k at (t&3)*16
            int n = tid >> 2, ks = (tid & 3) * 16;
            __align__(16) us tmp[16];
#pragma unroll
            for (int j = 0; j < 16; ++j) tmp[j] = T[ks + j][n];
            us* po = dst + (size_t)n * 512 + k0 + ks;
            *(uint4*)(po) = *(uint4*)(tmp);
            *(uint4*)(po + 8) = *(uint4*)(tmp + 8);
        }
        return;
    }
    {   // VTg ones row (row 64 of each chain)
        int e = (bid - 2304) * 1024 + tid * 4;
        int chain = e >> 11, s = e & 2047;
        ushort4 o; o.x = 0x3f80; o.y = 0x3f80; o.z = 0x3f80; o.w = 0x3f80;
        *(ushort4*)(VTg + ((size_t)(chain * 80 + 64)) * 2048 + s) = o;
    }
}

// ---------------- QKV GEMM: [4096,512]@[512,1536] -> Qg/Kg/Vg (elu on Q,K) --
__global__ __launch_bounds__(256)
void qkv_gemm(const us* __restrict__ A, const us* __restrict__ BT,
              us* __restrict__ Qg, us* __restrict__ Kg, us* __restrict__ Vg) {
    __shared__ __align__(16) us As[128 * 32];
    __shared__ __align__(16) us Bs[128 * 32];
    const int tid = threadIdx.x;
    const int w = tid >> 6, l = tid & 63;
    const int m0 = blockIdx.y * 128, n0 = blockIdx.x * 128;
    const int wm = (w >> 1) * 64, wn = (w & 1) * 64;
    floatx4 acc[4][4];
#pragma unroll
    for (int i = 0; i < 4; ++i)
#pragma unroll
        for (int j = 0; j < 4; ++j)
#pragma unroll
            for (int e = 0; e < 4; ++e) acc[i][j][e] = 0.f;

    for (int kt = 0; kt < 512; kt += 32) {
        __syncthreads();
#pragma unroll
        for (int r = 0; r < 2; ++r) {
            int slot = (r * 4 + w) * 64 + l;
            int row = slot >> 2, part = slot & 3;
            int g = part ^ (row & 3);
            gload_lds16(A + (size_t)(m0 + row) * 512 + kt + g * 8, As + (r * 4 + w) * 512);
            gload_lds16(BT + (size_t)(n0 + row) * 512 + kt + g * 8, Bs + (r * 4 + w) * 512);
        }
        __syncthreads();
        short8 a[4], b[4];
#pragma unroll
        for (int mi = 0; mi < 4; ++mi) {
            int row = wm + mi * 16 + (l & 15);
            int p = (l >> 4) ^ (row & 3);
            a[mi] = *(const short8*)(As + row * 32 + p * 8);
        }
#pragma unroll
        for (int ni = 0; ni < 4; ++ni) {
            int row = wn + ni * 16 + (l & 15);
            int p = (l >> 4) ^ (row & 3);
            b[ni] = *(const short8*)(Bs + row * 32 + p * 8);
        }
#pragma unroll
        for (int mi = 0; mi < 4; ++mi)
#pragma unroll
            for (int ni = 0; ni < 4; ++ni)
                acc[mi][ni] = mfma_bf16(a[mi], b[ni], acc[mi][ni]);
    }
    const int region = blockIdx.x >> 2;  // 0=Q 1=K 2=V
    us* outp = region == 0 ? Qg : (region == 1 ? Kg : Vg);
    const int cb = n0 - region * 512;
#pragma unroll
    for (int mi = 0; mi < 4; ++mi)
#pragma unroll
        for (int ni = 0; ni < 4; ++ni)
#pragma unroll
            for (int r = 0; r < 4; ++r) {
                int row = m0 + wm + mi * 16 + (l >> 4) * 4 + r;
                int col = cb + wn + ni * 16 + (l & 15);
                float v = acc[mi][ni][r];
                if (region < 2) v = elu1(v);
                outp[(size_t)row * 512 + col] = f2bf(v);
            }
}

// ---------------- per-chunk: C = [V^T;1] K^T + mirror V^T to VTg -----------
__global__ __launch_bounds__(256)
void chunk_kv_kernel(const us* __restrict__ Kg, const us* __restrict__ Vg,
                     float* __restrict__ KVc, us* __restrict__ VTg) {
    __shared__ __align__(16) us VT_l[80 * 72];
    __shared__ __align__(16) us KT_l[64 * 72];
    const int c = blockIdx.x, chain = blockIdx.y;
    const int b = chain >> 3, hh = chain & 7;
    const int tid = threadIdx.x;
    const int w = tid >> 6, l = tid & 63;
#pragma unroll
    for (int gi = 0; gi < 2; ++gi) {
        int g = w + gi * 4;
        __align__(16) us vv[8];
        __align__(16) us kk[8];
#pragma unroll
        for (int e = 0; e < 8; ++e) {
            size_t off = (size_t)((c * 64 + g * 8 + e) * 2 + b) * 512 + hh * 64 + l;
            vv[e] = Vg[off];
            kk[e] = Kg[off];
        }
        *(uint4*)(VT_l + l * 72 + g * 8) = *(uint4*)vv;
        *(uint4*)(KT_l + l * 72 + g * 8) = *(uint4*)kk;
        *(uint4*)(VTg + ((size_t)(chain * 80 + l)) * 2048 + c * 64 + g * 8) = *(uint4*)vv;
    }
    if (tid < 8) {
        ushort4 o; o.x = 0x3f80; o.y = 0x3f80; o.z = 0x3f80; o.w = 0x3f80;
        *(ushort4*)(VT_l + 64 * 72 + tid * 8) = o;
        *(ushort4*)(VT_l + 64 * 72 + tid * 8 + 4) = o;
    }
    __syncthreads();
    const int l15 = l & 15, l4 = l >> 4;
    short8 af[5][2], bfr[2];
#pragma unroll
    for (int mi = 0; mi < 5; ++mi) {
        int row = mi * 16 + l15;
        af[mi][0] = *(const short8*)(VT_l + row * 72 + l4 * 8);
        af[mi][1] = *(const short8*)(VT_l + row * 72 + 32 + l4 * 8);
    }
    {
        int row = w * 16 + l15;
        bfr[0] = *(const short8*)(KT_l + row * 72 + l4 * 8);
        bfr[1] = *(const short8*)(KT_l + row * 72 + 32 + l4 * 8);
    }
    float* out = KVc + (size_t)(chain * 32 + c) * 4608;
#pragma unroll
    for (int mi = 0; mi < 5; ++mi) {
        floatx4 a = {0.f, 0.f, 0.f, 0.f};
        a = mfma_bf16(af[mi][0], bfr[0], a);
        a = mfma_bf16(af[mi][1], bfr[1], a);
#pragma unroll
        for (int r = 0; r < 4; ++r) {
            int row = mi * 16 + l4 * 4 + r;
            if (row < 65) out[row * 64 + w * 16 + l15] = a[r];
        }
    }
}

// ---------------- exclusive prefix over chunks -> bf16 MTg -----------------
__global__ __launch_bounds__(256)
void cumsum_kernel(const float* __restrict__ KVc, us* __restrict__ MTg) {
    const int chain = blockIdx.x, rg = blockIdx.y;
    const int row = rg * 4 + (threadIdx.x >> 6), col = threadIdx.x & 63;
    const float* in = KVc + (size_t)chain * 32 * 4608 + row * 64 + col;
    us* out = MTg + ((size_t)chain * 32 * 80 + row) * 64 + col;
    float acc = 0.f;
#pragma unroll 4
    for (int cc = 0; cc < 32; ++cc) {
        out[(size_t)cc * 5120] = f2bf(acc);
        acc += in[(size_t)cc * 4608];
    }
}

// ---------------- MFMA attention, all operands LDS-staged ------------------
__global__ __launch_bounds__(256)
void attn_kernel(const us* __restrict__ Qg, const us* __restrict__ Kg,
                 const us* __restrict__ VTg, const us* __restrict__ MTg,
                 us* __restrict__ ATT) {
    __shared__ __align__(16) us Qs[64 * 64];
    __shared__ __align__(16) us Ks[64 * 64];
    __shared__ __align__(16) us Vs[80 * 64];
    __shared__ __align__(16) us Ms[80 * 64];
    __shared__ __align__(16) us Sl[64 * 64];
    const int c = blockIdx.x, chain = blockIdx.y;
    const int b = chain >> 3, hh = chain & 7;
    const int tid = threadIdx.x;
    const int w = tid >> 6, l = tid & 63;
    const int l15 = l & 15, l4 = l >> 4;
    const int lrow = l >> 3, lg = l & 7;

    // stage Q,K: 8 slots of 8 rows; V,M: 10 slots. XOR part swizzle via source.
#pragma unroll
    for (int r = 0; r < 2; ++r) {
        int slot = r * 4 + w;
        int row = slot * 8 + lrow;
        int g = lg ^ (row & 7);
        size_t grow = (size_t)((c * 64 + row) * 2 + b) * 512 + hh * 64 + g * 8;
        gload_lds16(Qg + grow, Qs + slot * 512);
        gload_lds16(Kg + grow, Ks + slot * 512);
    }
#pragma unroll
    for (int r = 0; r < 3; ++r) {
        int slot = r * 4 + w;
        if (slot < 10) {
            int row = slot * 8 + lrow;
            int g = lg ^ (row & 7);
            gload_lds16(VTg + (size_t)(chain * 80 + row) * 2048 + c * 64 + g * 8,
                        Vs + slot * 512);
            gload_lds16(MTg + ((size_t)(chain * 32 + c) * 80 + row) * 64 + g * 8,
                        Ms + slot * 512);
        }
    }
    __syncthreads();

    short8 qf[2];
    {
        int row = w * 16 + l15, p = l4 ^ (row & 7);
        qf[0] = *(const short8*)(Qs + row * 64 + p * 8);
        qf[1] = *(const short8*)(Qs + row * 64 + (p ^ 4) * 8);
    }
    short8 kf[4][2];
#pragma unroll
    for (int ni = 0; ni < 4; ++ni) {
        int row = ni * 16 + l15, p = l4 ^ (row & 7);
        kf[ni][0] = *(const short8*)(Ks + row * 64 + p * 8);
        kf[ni][1] = *(const short8*)(Ks + row * 64 + (p ^ 4) * 8);
    }
    short8 vf[5][2], mf[5][2];
#pragma unroll
    for (int ni = 0; ni < 5; ++ni) {
        int row = ni * 16 + l15, p = l4 ^ (row & 7);
        vf[ni][0] = *(const short8*)(Vs + row * 64 + p * 8);
        vf[ni][1] = *(const short8*)(Vs + row * 64 + (p ^ 4) * 8);
        mf[ni][0] = *(const short8*)(Ms + row * 64 + p * 8);
        mf[ni][1] = *(const short8*)(Ms + row * 64 + (p ^ 4) * 8);
    }

    // phase 1: S = Q @ K^T, causal mask, -> bf16 Sl (XOR-swizzled parts)
    const int ibase = w * 16 + l4 * 4;
#pragma unroll
    for (int ni = 0; ni < 4; ++ni) {
        floatx4 s = {0.f, 0.f, 0.f, 0.f};
        s = mfma_bf16(qf[0], kf[ni][0], s);
        s = mfma_bf16(qf[1], kf[ni][1], s);
        int col = ni * 16 + l15;
#pragma unroll
        for (int r = 0; r < 4; ++r) {
            int i = ibase + r;
            float v = (col <= i) ? s[r] : 0.f;
            Sl[i * 64 + (((col >> 3) ^ (i & 7)) * 8) + (col & 7)] = f2bf(v);
        }
    }
    __syncthreads();

    short8 sf[2];
    {
        int ir = w * 16 + l15;
        sf[0] = *(const short8*)(Sl + ir * 64 + ((l4 ^ (ir & 7)) * 8));
        sf[1] = *(const short8*)(Sl + ir * 64 + (((4 + l4) ^ (ir & 7)) * 8));
    }

    // phases 2+3: acc = S@[V^T;1]^T + Q@[Mp;Sprev]^T ; tile 4 col 64 = denom
    floatx4 acc[5];
#pragma unroll
    for (int ni = 0; ni < 5; ++ni) {
        floatx4 a = {0.f, 0.f, 0.f, 0.f};
        a = mfma_bf16(sf[0], vf[ni][0], a);
        a = mfma_bf16(sf[1], vf[ni][1], a);
        a = mfma_bf16(qf[0], mf[ni][0], a);
        a = mfma_bf16(qf[1], mf[ni][1], a);
        acc[ni] = a;
    }

    float fac[4];
#pragma unroll
    for (int r = 0; r < 4; ++r) {
        float den = __shfl(acc[4][r], l & 48, 64);
        fac[r] = SCALE / (SCALE * den + EPS);
    }
#pragma unroll
    for (int ni = 0; ni < 4; ++ni)
#pragma unroll
        for (int r = 0; r < 4; ++r) {
            int i = ibase + r;
            ATT[((size_t)((c * 64 + i) * 2 + b)) * 512 + hh * 64 + ni * 16 + l15] =
                f2bf(acc[ni][r] * fac[r]);
        }
}

// ---------------- fused Wo GEMM + residual + LayerNorm ---------------------
// BM=32, BN=512 (full width), 4 waves each 32x128; grid = 128 blocks.
__global__ __launch_bounds__(256)
void wo_ln_kernel(const us* __restrict__ ATT, const us* __restrict__ WoT,
                  const float* __restrict__ h, const float* __restrict__ gamma,
                  const float* __restrict__ beta, float* __restrict__ out) {
    __shared__ __align__(16) us As[32 * 32];
    __shared__ __align__(16) us Bs[512 * 32];
    __shared__ float redS[4][32];
    __shared__ float redQ[4][32];
    __shared__ float mml[32], rsl[32];
    const int tid = threadIdx.x;
    const int w = tid >> 6, l = tid & 63;
    const int l15 = l & 15, l4 = l >> 4;
    const int m0 = blockIdx.x * 32, wn = w * 128;
    floatx4 acc[2][8];
#pragma unroll
    for (int i = 0; i < 2; ++i)
#pragma unroll
        for (int j = 0; j < 8; ++j)
#pragma unroll
            for (int e = 0; e < 4; ++e) acc[i][j][e] = 0.f;

    for (int kt = 0; kt < 512; kt += 32) {
        __syncthreads();
#pragma unroll
        for (int r = 0; r < 8; ++r) {
            int slot = r * 4 + w;
            int row = slot * 16 + (l >> 2);
            int g = (l & 3) ^ (row & 3);
            gload_lds16(WoT + (size_t)row * 512 + kt + g * 8, Bs + slot * 512);
        }
        if (w < 2) {
            int row = w * 16 + (l >> 2);
            int g = (l & 3) ^ (row & 3);
            gload_lds16(ATT + (size_t)(m0 + row) * 512 + kt + g * 8, As + w * 512);
        }
        __syncthreads();
        short8 af[2], bf[8];
#pragma unroll
        for (int mi = 0; mi < 2; ++mi) {
            int row = mi * 16 + l15, p = l4 ^ (row & 3);
            af[mi] = *(const short8*)(As + row * 32 + p * 8);
        }
#pragma unroll
        for (int ni = 0; ni < 8; ++ni) {
            int row = wn + ni * 16 + l15, p = l4 ^ (row & 3);
            bf[ni] = *(const short8*)(Bs + row * 32 + p * 8);
        }
#pragma unroll
        for (int mi = 0; mi < 2; ++mi)
#pragma unroll
            for (int ni = 0; ni < 8; ++ni)
                acc[mi][ni] = mfma_bf16(af[mi], bf[ni], acc[mi][ni]);
    }

    // x = acc + h ; per-row sum/sumsq: in-lane over ni, shfl over l15, LDS over waves
#pragma unroll
    for (int mi = 0; mi < 2; ++mi)
#pragma unroll
        for (int r = 0; r < 4; ++r) {
            int row = mi * 16 + l4 * 4 + r;
            const float* hrow = h + (size_t)(m0 + row) * 512 + wn + l15;
            float s = 0.f, q = 0.f;
#pragma unroll
            for (int ni = 0; ni < 8; ++ni) {
                float x = acc[mi][ni][r] + hrow[ni * 16];
                acc[mi][ni][r] = x;
                s += x;
                q = fmaf(x, x, q);
            }
#pragma unroll
            for (int off = 1; off <= 8; off <<= 1) {
                s += __shfl_xor(s, off, 64);
                q += __shfl_xor(q, off, 64);
            }
            if (l15 == 0) { redS[w][row] = s; redQ[w][row] = q; }
        }
    __syncthreads();
    if (tid < 32) {
        float s = redS[0][tid] + redS[1][tid] + redS[2][tid] + redS[3][tid];
        float q = redQ[0][tid] + redQ[1][tid] + redQ[2][tid] + redQ[3][tid];
        float mean = s * (1.f / 512);
        float var = q * (1.f / 512) - mean * mean;
        mml[tid] = mean;
        rsl[tid] = rsqrtf(var + LN_EPS);
    }
    __syncthreads();
#pragma unroll
    for (int mi = 0; mi < 2; ++mi)
#pragma unroll
        for (int r = 0; r < 4; ++r) {
            int row = mi * 16 + l4 * 4 + r;
            float mean = mml[row], rstd = rsl[row];
#pragma unroll
            for (int ni = 0; ni < 8; ++ni) {
                int col = wn + ni * 16 + l15;
                out[(size_t)(m0 + row) * 512 + col] =
                    (acc[mi][ni][r] - mean) * rstd * gamma[col] + beta[col];
            }
        }
}

extern "C" void kernel_launch(void* const* d_in, const int* in_sizes, int n_in,
                              void* d_out, int out_size, void* d_ws, size_t ws_size,
                              hipStream_t stream) {
    const float* h = (const float*)d_in[0];
    const float* Wq = (const float*)d_in[1];
    const float* Wkv = (const float*)d_in[2];
    const float* Wo = (const float*)d_in[3];
    const float* gamma = (const float*)d_in[4];
    const float* beta = (const float*)d_in[5];

    char* ws = (char*)d_ws;
    us* Qg      = (us*)(ws + 0);          //  4 MB
    us* Kg      = (us*)(ws + 4194304);    //  4 MB
    us* Vg      = (us*)(ws + 8388608);    //  4 MB
    us* VTg     = (us*)(ws + 12582912);   //  5.25 MB [16][80][2048]
    us* ATT     = (us*)(ws + 17825792);   //  4 MB
    us* WoT     = (us*)(ws + 22020096);   //  0.5 MB
    us* MTg     = (us*)(ws + 22544384);   //  5.25 MB [16][32][80][64]
    us* hB      = (us*)(ws + 27787264);   //  4 MB
    us* WqkvT   = (us*)(ws + 31981568);   //  1.5 MB
    float* KVc  = (float*)(ws + 33554432);//  9.44 MB

    dim3 blk(256);
    pack_kernel<<<2336, blk, 0, stream>>>(h, Wq, Wkv, Wo, hB, WqkvT, WoT, VTg);
    qkv_gemm<<<dim3(12, 32), blk, 0, stream>>>(hB, WqkvT, Qg, Kg, Vg);
    chunk_kv_kernel<<<dim3(32, 16), blk, 0, stream>>>(Kg, Vg, KVc, VTg);
    cumsum_kernel<<<dim3(16, 17), blk, 0, stream>>>(KVc, MTg);
    attn_kernel<<<dim3(32, 16), blk, 0, stream>>>(Qg, Kg, VTg, MTg, ATT);
    wo_ln_kernel<<<128, blk, 0, stream>>>(ATT, WoT, h, gamma, beta, (float*)d_out);
}

// Round 5
// 134.687 us; speedup vs baseline: 3.7085x; 1.0324x over previous
//
#include <hip/hip_runtime.h>
#include <hip/hip_bf16.h>
#include <math.h>

#define SCALE 0.125f
#define EPS 1e-5f
#define LN_EPS 1e-5f

typedef short short8 __attribute__((ext_vector_type(8)));
typedef float floatx4 __attribute__((ext_vector_type(4)));
typedef unsigned short us;

__device__ __forceinline__ float elu1(float x) { return x > 0.f ? x + 1.f : __expf(x); }
__device__ __forceinline__ us f2bf(float f) {
    __hip_bfloat16 b = __float2bfloat16(f);
    return __builtin_bit_cast(us, b);
}
__device__ __forceinline__ void gload_lds16(const void* g, void* lds) {
    __builtin_amdgcn_global_load_lds(
        (const __attribute__((address_space(1))) unsigned int*)g,
        (__attribute__((address_space(3))) unsigned int*)lds, 16, 0, 0);
}
__device__ __forceinline__ floatx4 mfma_bf16(short8 a, short8 b, floatx4 c) {
    return __builtin_amdgcn_mfma_f32_16x16x32_bf16(a, b, c, 0, 0, 0);
}

// ---------------- pack: h->bf16 (coalesced), LDS-tiled weight transposes ----
__global__ __launch_bounds__(256)
void pack_kernel(const float* __restrict__ h, const float* __restrict__ Wq,
                 const float* __restrict__ Wkv, const float* __restrict__ Wo,
                 us* __restrict__ hB, us* __restrict__ WqkvT, us* __restrict__ WoT,
                 us* __restrict__ VTg) {
    const int bid = blockIdx.x, tid = threadIdx.x;
    if (bid < 2048) {
        int idx = bid * 1024 + tid * 4;
        float4 v = *(const float4*)(h + idx);
        ushort4 o;
        o.x = f2bf(v.x); o.y = f2bf(v.y); o.z = f2bf(v.z); o.w = f2bf(v.w);
        *(ushort4*)(hB + idx) = o;
        return;
    }
    if (bid < 2304) {
        __shared__ us T[64][72];
        const float* src; int ld, n0s, k0; us* dst;
        if (bid < 2240) {
            int t2 = bid - 2048;           // Wqkv: 24 n-tiles x 8 k-tiles
            int nt = t2 % 24, kt = t2 / 24;
            int n0 = nt * 64; k0 = kt * 64;
            if (n0 < 512) { src = Wq; ld = 512; n0s = n0; }
            else          { src = Wkv; ld = 1024; n0s = n0 - 512; }
            dst = WqkvT + (size_t)n0 * 512;
        } else {
            int t2 = bid - 2240;           // Wo: 8 x 8
            int nt = t2 & 7, kt = t2 >> 3;
            src = Wo; ld = 512; n0s = nt * 64; k0 = kt * 64;
            dst = WoT + (size_t)(nt * 64) * 512;
        }
        {
            int k = tid >> 2, cs = (tid & 3) * 16;
            const float* p = src + (size_t)(k0 + k) * ld + n0s + cs;
#pragma unroll
            for (int q = 0; q < 4; ++q) {
                float4 v = *(const float4*)(p + q * 4);
                T[k][cs + q * 4 + 0] = f2bf(v.x);
                T[k][cs + q * 4 + 1] = f2bf(v.y);
                T[k][cs + q * 4 + 2] = f2bf(v.z);
                T[k][cs + q * 4 + 3] = f2bf(v.w);
            }
        }
        __syncthreads();
        {
            int n = tid >> 2, ks = (tid & 3) * 16;
            __align__(16) us tmp[16];
#pragma unroll
            for (int j = 0; j < 16; ++j) tmp[j] = T[ks + j][n];
            us* po = dst + (size_t)n * 512 + k0 + ks;
            *(uint4*)(po) = *(uint4*)(tmp);
            *(uint4*)(po + 8) = *(uint4*)(tmp + 8);
        }
        return;
    }
    {   // VTg ones row (row 64 of each chain)
        int e = (bid - 2304) * 1024 + tid * 4;
        int chain = e >> 11, s = e & 2047;
        ushort4 o; o.x = 0x3f80; o.y = 0x3f80; o.z = 0x3f80; o.w = 0x3f80;
        *(ushort4*)(VTg + ((size_t)(chain * 80 + 64)) * 2048 + s) = o;
    }
}

// ---------------- QKV GEMM, 2-phase double-buffered ------------------------
__global__ __launch_bounds__(256)
void qkv_gemm(const us* __restrict__ A, const us* __restrict__ BT,
              us* __restrict__ Qg, us* __restrict__ Kg, us* __restrict__ Vg) {
    __shared__ __align__(16) us As[2][128 * 32];
    __shared__ __align__(16) us Bs[2][128 * 32];
    const int tid = threadIdx.x;
    const int w = tid >> 6, l = tid & 63;
    const int m0 = blockIdx.y * 128, n0 = blockIdx.x * 128;
    const int wm = (w >> 1) * 64, wn = (w & 1) * 64;
    floatx4 acc[4][4];
#pragma unroll
    for (int i = 0; i < 4; ++i)
#pragma unroll
        for (int j = 0; j < 4; ++j)
#pragma unroll
            for (int e = 0; e < 4; ++e) acc[i][j][e] = 0.f;

    auto STAGE = [&](int buf, int kt) {
#pragma unroll
        for (int r = 0; r < 2; ++r) {
            int slot = (r * 4 + w) * 64 + l;
            int row = slot >> 2, part = slot & 3;
            int g = part ^ (row & 3);
            gload_lds16(A + (size_t)(m0 + row) * 512 + kt + g * 8, &As[buf][(r * 4 + w) * 512]);
            gload_lds16(BT + (size_t)(n0 + row) * 512 + kt + g * 8, &Bs[buf][(r * 4 + w) * 512]);
        }
    };

    STAGE(0, 0);
    __syncthreads();
    for (int t = 0; t < 16; ++t) {
        int cur = t & 1;
        if (t < 15) STAGE(cur ^ 1, (t + 1) * 32);  // loads fly over this tile's compute
        short8 a[4], b[4];
#pragma unroll
        for (int mi = 0; mi < 4; ++mi) {
            int row = wm + mi * 16 + (l & 15);
            int p = (l >> 4) ^ (row & 3);
            a[mi] = *(const short8*)(&As[cur][row * 32 + p * 8]);
        }
#pragma unroll
        for (int ni = 0; ni < 4; ++ni) {
            int row = wn + ni * 16 + (l & 15);
            int p = (l >> 4) ^ (row & 3);
            b[ni] = *(const short8*)(&Bs[cur][row * 32 + p * 8]);
        }
#pragma unroll
        for (int mi = 0; mi < 4; ++mi)
#pragma unroll
            for (int ni = 0; ni < 4; ++ni)
                acc[mi][ni] = mfma_bf16(a[mi], b[ni], acc[mi][ni]);
        __syncthreads();  // drains vmcnt(0): next tile staged, cur free for reuse
    }
    const int region = blockIdx.x >> 2;  // 0=Q 1=K 2=V
    us* outp = region == 0 ? Qg : (region == 1 ? Kg : Vg);
    const int cb = n0 - region * 512;
#pragma unroll
    for (int mi = 0; mi < 4; ++mi)
#pragma unroll
        for (int ni = 0; ni < 4; ++ni)
#pragma unroll
            for (int r = 0; r < 4; ++r) {
                int row = m0 + wm + mi * 16 + (l >> 4) * 4 + r;
                int col = cb + wn + ni * 16 + (l & 15);
                float v = acc[mi][ni][r];
                if (region < 2) v = elu1(v);
                outp[(size_t)row * 512 + col] = f2bf(v);
            }
}

// ---------------- per-chunk: C = [V^T;1] K^T + mirror V^T to VTg -----------
__global__ __launch_bounds__(256)
void chunk_kv_kernel(const us* __restrict__ Kg, const us* __restrict__ Vg,
                     float* __restrict__ KVc, us* __restrict__ VTg) {
    __shared__ __align__(16) us VT_l[80 * 72];
    __shared__ __align__(16) us KT_l[64 * 72];
    const int c = blockIdx.x, chain = blockIdx.y;
    const int b = chain >> 3, hh = chain & 7;
    const int tid = threadIdx.x;
    const int w = tid >> 6, l = tid & 63;
#pragma unroll
    for (int gi = 0; gi < 2; ++gi) {
        int g = w + gi * 4;
        __align__(16) us vv[8];
        __align__(16) us kk[8];
#pragma unroll
        for (int e = 0; e < 8; ++e) {
            size_t off = (size_t)((c * 64 + g * 8 + e) * 2 + b) * 512 + hh * 64 + l;
            vv[e] = Vg[off];
            kk[e] = Kg[off];
        }
        *(uint4*)(VT_l + l * 72 + g * 8) = *(uint4*)vv;
        *(uint4*)(KT_l + l * 72 + g * 8) = *(uint4*)kk;
        *(uint4*)(VTg + ((size_t)(chain * 80 + l)) * 2048 + c * 64 + g * 8) = *(uint4*)vv;
    }
    if (tid < 8) {
        ushort4 o; o.x = 0x3f80; o.y = 0x3f80; o.z = 0x3f80; o.w = 0x3f80;
        *(ushort4*)(VT_l + 64 * 72 + tid * 8) = o;
        *(ushort4*)(VT_l + 64 * 72 + tid * 8 + 4) = o;
    }
    __syncthreads();
    const int l15 = l & 15, l4 = l >> 4;
    short8 af[5][2], bfr[2];
#pragma unroll
    for (int mi = 0; mi < 5; ++mi) {
        int row = mi * 16 + l15;
        af[mi][0] = *(const short8*)(VT_l + row * 72 + l4 * 8);
        af[mi][1] = *(const short8*)(VT_l + row * 72 + 32 + l4 * 8);
    }
    {
        int row = w * 16 + l15;
        bfr[0] = *(const short8*)(KT_l + row * 72 + l4 * 8);
        bfr[1] = *(const short8*)(KT_l + row * 72 + 32 + l4 * 8);
    }
    float* out = KVc + (size_t)(chain * 32 + c) * 4608;
#pragma unroll
    for (int mi = 0; mi < 5; ++mi) {
        floatx4 a = {0.f, 0.f, 0.f, 0.f};
        a = mfma_bf16(af[mi][0], bfr[0], a);
        a = mfma_bf16(af[mi][1], bfr[1], a);
#pragma unroll
        for (int r = 0; r < 4; ++r) {
            int row = mi * 16 + l4 * 4 + r;
            if (row < 65) out[row * 64 + w * 16 + l15] = a[r];
        }
    }
}

// ---------------- exclusive prefix over chunks -> bf16 MTg -----------------
__global__ __launch_bounds__(256)
void cumsum_kernel(const float* __restrict__ KVc, us* __restrict__ MTg) {
    const int chain = blockIdx.x, rg = blockIdx.y;
    const int row = rg * 4 + (threadIdx.x >> 6), col = threadIdx.x & 63;
    const float* in = KVc + (size_t)chain * 32 * 4608 + row * 64 + col;
    us* out = MTg + ((size_t)chain * 32 * 80 + row) * 64 + col;
    float acc = 0.f;
#pragma unroll 4
    for (int cc = 0; cc < 32; ++cc) {
        out[(size_t)cc * 5120] = f2bf(acc);
        acc += in[(size_t)cc * 4608];
    }
}

// ---------------- MFMA attention, all operands LDS-staged ------------------
__global__ __launch_bounds__(256)
void attn_kernel(const us* __restrict__ Qg, const us* __restrict__ Kg,
                 const us* __restrict__ VTg, const us* __restrict__ MTg,
                 us* __restrict__ ATT) {
    __shared__ __align__(16) us Qs[64 * 64];
    __shared__ __align__(16) us Ks[64 * 64];
    __shared__ __align__(16) us Vs[80 * 64];
    __shared__ __align__(16) us Ms[80 * 64];
    __shared__ __align__(16) us Sl[64 * 64];
    const int c = blockIdx.x, chain = blockIdx.y;
    const int b = chain >> 3, hh = chain & 7;
    const int tid = threadIdx.x;
    const int w = tid >> 6, l = tid & 63;
    const int l15 = l & 15, l4 = l >> 4;
    const int lrow = l >> 3, lg = l & 7;

#pragma unroll
    for (int r = 0; r < 2; ++r) {
        int slot = r * 4 + w;
        int row = slot * 8 + lrow;
        int g = lg ^ (row & 7);
        size_t grow = (size_t)((c * 64 + row) * 2 + b) * 512 + hh * 64 + g * 8;
        gload_lds16(Qg + grow, Qs + slot * 512);
        gload_lds16(Kg + grow, Ks + slot * 512);
    }
#pragma unroll
    for (int r = 0; r < 3; ++r) {
        int slot = r * 4 + w;
        if (slot < 10) {
            int row = slot * 8 + lrow;
            int g = lg ^ (row & 7);
            gload_lds16(VTg + (size_t)(chain * 80 + row) * 2048 + c * 64 + g * 8,
                        Vs + slot * 512);
            gload_lds16(MTg + ((size_t)(chain * 32 + c) * 80 + row) * 64 + g * 8,
                        Ms + slot * 512);
        }
    }
    __syncthreads();

    short8 qf[2];
    {
        int row = w * 16 + l15, p = l4 ^ (row & 7);
        qf[0] = *(const short8*)(Qs + row * 64 + p * 8);
        qf[1] = *(const short8*)(Qs + row * 64 + (p ^ 4) * 8);
    }
    short8 kf[4][2];
#pragma unroll
    for (int ni = 0; ni < 4; ++ni) {
        int row = ni * 16 + l15, p = l4 ^ (row & 7);
        kf[ni][0] = *(const short8*)(Ks + row * 64 + p * 8);
        kf[ni][1] = *(const short8*)(Ks + row * 64 + (p ^ 4) * 8);
    }
    short8 vf[5][2], mf[5][2];
#pragma unroll
    for (int ni = 0; ni < 5; ++ni) {
        int row = ni * 16 + l15, p = l4 ^ (row & 7);
        vf[ni][0] = *(const short8*)(Vs + row * 64 + p * 8);
        vf[ni][1] = *(const short8*)(Vs + row * 64 + (p ^ 4) * 8);
        mf[ni][0] = *(const short8*)(Ms + row * 64 + p * 8);
        mf[ni][1] = *(const short8*)(Ms + row * 64 + (p ^ 4) * 8);
    }

    const int ibase = w * 16 + l4 * 4;
#pragma unroll
    for (int ni = 0; ni < 4; ++ni) {
        floatx4 s = {0.f, 0.f, 0.f, 0.f};
        s = mfma_bf16(qf[0], kf[ni][0], s);
        s = mfma_bf16(qf[1], kf[ni][1], s);
        int col = ni * 16 + l15;
#pragma unroll
        for (int r = 0; r < 4; ++r) {
            int i = ibase + r;
            float v = (col <= i) ? s[r] : 0.f;
            Sl[i * 64 + (((col >> 3) ^ (i & 7)) * 8) + (col & 7)] = f2bf(v);
        }
    }
    __syncthreads();

    short8 sf[2];
    {
        int ir = w * 16 + l15;
        sf[0] = *(const short8*)(Sl + ir * 64 + ((l4 ^ (ir & 7)) * 8));
        sf[1] = *(const short8*)(Sl + ir * 64 + (((4 + l4) ^ (ir & 7)) * 8));
    }

    floatx4 acc[5];
#pragma unroll
    for (int ni = 0; ni < 5; ++ni) {
        floatx4 a = {0.f, 0.f, 0.f, 0.f};
        a = mfma_bf16(sf[0], vf[ni][0], a);
        a = mfma_bf16(sf[1], vf[ni][1], a);
        a = mfma_bf16(qf[0], mf[ni][0], a);
        a = mfma_bf16(qf[1], mf[ni][1], a);
        acc[ni] = a;
    }

    float fac[4];
#pragma unroll
    for (int r = 0; r < 4; ++r) {
        float den = __shfl(acc[4][r], l & 48, 64);
        fac[r] = SCALE / (SCALE * den + EPS);
    }
#pragma unroll
    for (int ni = 0; ni < 4; ++ni)
#pragma unroll
        for (int r = 0; r < 4; ++r) {
            int i = ibase + r;
            ATT[((size_t)((c * 64 + i) * 2 + b)) * 512 + hh * 64 + ni * 16 + l15] =
                f2bf(acc[ni][r] * fac[r]);
        }
}

// ---------------- fused Wo GEMM + residual + LayerNorm ---------------------
// BM=16, BN=512 (full width), 4 waves each 16x128; grid = 256 blocks.
__global__ __launch_bounds__(256)
void wo_ln_kernel(const us* __restrict__ ATT, const us* __restrict__ WoT,
                  const float* __restrict__ h, const float* __restrict__ gamma,
                  const float* __restrict__ beta, float* __restrict__ out) {
    __shared__ __align__(16) us As[2][16 * 32];
    __shared__ __align__(16) us Bs[2][512 * 32];
    __shared__ float redS[4][16];
    __shared__ float redQ[4][16];
    __shared__ float mml[16], rsl[16];
    const int tid = threadIdx.x;
    const int w = tid >> 6, l = tid & 63;
    const int l15 = l & 15, l4 = l >> 4;
    const int m0 = blockIdx.x * 16, wn = w * 128;
    floatx4 acc[8];
#pragma unroll
    for (int j = 0; j < 8; ++j)
#pragma unroll
        for (int e = 0; e < 4; ++e) acc[j][e] = 0.f;

    auto STAGE = [&](int buf, int kt) {
#pragma unroll
        for (int r = 0; r < 8; ++r) {
            int slot = r * 4 + w;
            int row = slot * 16 + (l >> 2);
            int g = (l & 3) ^ (row & 3);
            gload_lds16(WoT + (size_t)row * 512 + kt + g * 8, &Bs[buf][slot * 512]);
        }
        if (w == 0) {
            int row = l >> 2;
            int g = (l & 3) ^ (row & 3);
            gload_lds16(ATT + (size_t)(m0 + row) * 512 + kt + g * 8, &As[buf][0]);
        }
    };

    STAGE(0, 0);
    __syncthreads();
    for (int t = 0; t < 16; ++t) {
        int cur = t & 1;
        if (t < 15) STAGE(cur ^ 1, (t + 1) * 32);
        short8 af, bf[8];
        {
            int row = l15, p = l4 ^ (row & 3);
            af = *(const short8*)(&As[cur][row * 32 + p * 8]);
        }
#pragma unroll
        for (int ni = 0; ni < 8; ++ni) {
            int row = wn + ni * 16 + l15, p = l4 ^ (row & 3);
            bf[ni] = *(const short8*)(&Bs[cur][row * 32 + p * 8]);
        }
#pragma unroll
        for (int ni = 0; ni < 8; ++ni)
            acc[ni] = mfma_bf16(af, bf[ni], acc[ni]);
        __syncthreads();
    }

    // x = acc + h ; row stats: in-lane over ni, shfl over l15-group, LDS over waves
#pragma unroll
    for (int r = 0; r < 4; ++r) {
        int row = l4 * 4 + r;
        const float* hrow = h + (size_t)(m0 + row) * 512 + wn + l15;
        float s = 0.f, q = 0.f;
#pragma unroll
        for (int ni = 0; ni < 8; ++ni) {
            float x = acc[ni][r] + hrow[ni * 16];
            acc[ni][r] = x;
            s += x;
            q = fmaf(x, x, q);
        }
#pragma unroll
        for (int off = 1; off <= 8; off <<= 1) {
            s += __shfl_xor(s, off, 64);
            q += __shfl_xor(q, off, 64);
        }
        if (l15 == 0) { redS[w][row] = s; redQ[w][row] = q; }
    }
    __syncthreads();
    if (tid < 16) {
        float s = redS[0][tid] + redS[1][tid] + redS[2][tid] + redS[3][tid];
        float q = redQ[0][tid] + redQ[1][tid] + redQ[2][tid] + redQ[3][tid];
        float mean = s * (1.f / 512);
        float var = q * (1.f / 512) - mean * mean;
        mml[tid] = mean;
        rsl[tid] = rsqrtf(var + LN_EPS);
    }
    __syncthreads();
#pragma unroll
    for (int r = 0; r < 4; ++r) {
        int row = l4 * 4 + r;
        float mean = mml[row], rstd = rsl[row];
#pragma unroll
        for (int ni = 0; ni < 8; ++ni) {
            int col = wn + ni * 16 + l15;
            out[(size_t)(m0 + row) * 512 + col] =
                (acc[ni][r] - mean) * rstd * gamma[col] + beta[col];
        }
    }
}

extern "C" void kernel_launch(void* const* d_in, const int* in_sizes, int n_in,
                              void* d_out, int out_size, void* d_ws, size_t ws_size,
                              hipStream_t stream) {
    const float* h = (const float*)d_in[0];
    const float* Wq = (const float*)d_in[1];
    const float* Wkv = (const float*)d_in[2];
    const float* Wo = (const float*)d_in[3];
    const float* gamma = (const float*)d_in[4];
    const float* beta = (const float*)d_in[5];

    char* ws = (char*)d_ws;
    us* Qg      = (us*)(ws + 0);          //  4 MB
    us* Kg      = (us*)(ws + 4194304);    //  4 MB
    us* Vg      = (us*)(ws + 8388608);    //  4 MB
    us* VTg     = (us*)(ws + 12582912);   //  5.25 MB [16][80][2048]
    us* ATT     = (us*)(ws + 17825792);   //  4 MB
    us* WoT     = (us*)(ws + 22020096);   //  0.5 MB
    us* MTg     = (us*)(ws + 22544384);   //  5.25 MB [16][32][80][64]
    us* hB      = (us*)(ws + 27787264);   //  4 MB
    us* WqkvT   = (us*)(ws + 31981568);   //  1.5 MB
    float* KVc  = (float*)(ws + 33554432);//  9.44 MB

    dim3 blk(256);
    pack_kernel<<<2336, blk, 0, stream>>>(h, Wq, Wkv, Wo, hB, WqkvT, WoT, VTg);
    qkv_gemm<<<dim3(12, 32), blk, 0, stream>>>(hB, WqkvT, Qg, Kg, Vg);
    chunk_kv_kernel<<<dim3(32, 16), blk, 0, stream>>>(Kg, Vg, KVc, VTg);
    cumsum_kernel<<<dim3(16, 17), blk, 0, stream>>>(KVc, MTg);
    attn_kernel<<<dim3(32, 16), blk, 0, stream>>>(Qg, Kg, VTg, MTg, ATT);
    wo_ln_kernel<<<256, blk, 0, stream>>>(ATT, WoT, h, gamma, beta, (float*)d_out);
}

// Round 7
// 132.738 us; speedup vs baseline: 3.7630x; 1.0147x over previous
//
#include <hip/hip_runtime.h>
#include <hip/hip_bf16.h>
#include <math.h>

#define SCALE 0.125f
#define EPS 1e-5f
#define LN_EPS 1e-5f

typedef short short8 __attribute__((ext_vector_type(8)));
typedef float floatx4 __attribute__((ext_vector_type(4)));
typedef unsigned short us;

__device__ __forceinline__ float elu1(float x) { return x > 0.f ? x + 1.f : __expf(x); }
__device__ __forceinline__ us f2bf(float f) {
    __hip_bfloat16 b = __float2bfloat16(f);
    return __builtin_bit_cast(us, b);
}
__device__ __forceinline__ void gload_lds16(const void* g, void* lds) {
    __builtin_amdgcn_global_load_lds(
        (const __attribute__((address_space(1))) unsigned int*)g,
        (__attribute__((address_space(3))) unsigned int*)lds, 16, 0, 0);
}
__device__ __forceinline__ floatx4 mfma_bf16(short8 a, short8 b, floatx4 c) {
    return __builtin_amdgcn_mfma_f32_16x16x32_bf16(a, b, c, 0, 0, 0);
}

// ---------------- pack: h->bf16 (coalesced), LDS-tiled weight transposes ----
__global__ __launch_bounds__(256)
void pack_kernel(const float* __restrict__ h, const float* __restrict__ Wq,
                 const float* __restrict__ Wkv, const float* __restrict__ Wo,
                 us* __restrict__ hB, us* __restrict__ WqkvT, us* __restrict__ WoT,
                 us* __restrict__ VTg) {
    const int bid = blockIdx.x, tid = threadIdx.x;
    if (bid < 2048) {
        int idx = bid * 1024 + tid * 4;
        float4 v = *(const float4*)(h + idx);
        ushort4 o;
        o.x = f2bf(v.x); o.y = f2bf(v.y); o.z = f2bf(v.z); o.w = f2bf(v.w);
        *(ushort4*)(hB + idx) = o;
        return;
    }
    if (bid < 2304) {
        __shared__ us T[64][72];
        const float* src; int ld, n0s, k0; us* dst;
        if (bid < 2240) {
            int t2 = bid - 2048;           // Wqkv: 24 n-tiles x 8 k-tiles
            int nt = t2 % 24, kt = t2 / 24;
            int n0 = nt * 64; k0 = kt * 64;
            if (n0 < 512) { src = Wq; ld = 512; n0s = n0; }
            else          { src = Wkv; ld = 1024; n0s = n0 - 512; }
            dst = WqkvT + (size_t)n0 * 512;
        } else {
            int t2 = bid - 2240;           // Wo: 8 x 8
            int nt = t2 & 7, kt = t2 >> 3;
            src = Wo; ld = 512; n0s = nt * 64; k0 = kt * 64;
            dst = WoT + (size_t)(nt * 64) * 512;
        }
        {
            int k = tid >> 2, cs = (tid & 3) * 16;
            const float* p = src + (size_t)(k0 + k) * ld + n0s + cs;
#pragma unroll
            for (int q = 0; q < 4; ++q) {
                float4 v = *(const float4*)(p + q * 4);
                T[k][cs + q * 4 + 0] = f2bf(v.x);
                T[k][cs + q * 4 + 1] = f2bf(v.y);
                T[k][cs + q * 4 + 2] = f2bf(v.z);
                T[k][cs + q * 4 + 3] = f2bf(v.w);
            }
        }
        __syncthreads();
        {
            int n = tid >> 2, ks = (tid & 3) * 16;
            __align__(16) us tmp[16];
#pragma unroll
            for (int j = 0; j < 16; ++j) tmp[j] = T[ks + j][n];
            us* po = dst + (size_t)n * 512 + k0 + ks;
            *(uint4*)(po) = *(uint4*)(tmp);
            *(uint4*)(po + 8) = *(uint4*)(tmp + 8);
        }
        return;
    }
    {   // VTg ones row (row 64 of each chain)
        int e = (bid - 2304) * 1024 + tid * 4;
        int chain = e >> 11, s = e & 2047;
        ushort4 o; o.x = 0x3f80; o.y = 0x3f80; o.z = 0x3f80; o.w = 0x3f80;
        *(ushort4*)(VTg + ((size_t)(chain * 80 + 64)) * 2048 + s) = o;
    }
}

// ---------------- QKV GEMM: BM=64 (grid 768 = 3.0 CU-waves), dbuf ----------
// V region writes VTg (transposed) directly; Q/K regions row-major with elu.
__global__ __launch_bounds__(256)
void qkv_gemm(const us* __restrict__ A, const us* __restrict__ BT,
              us* __restrict__ Qg, us* __restrict__ Kg, us* __restrict__ VTg) {
    __shared__ __align__(16) us As[2][64 * 32];
    __shared__ __align__(16) us Bs[2][128 * 32];
    const int tid = threadIdx.x;
    const int w = tid >> 6, l = tid & 63;
    const int l15 = l & 15, l4 = l >> 4;
    const int bx = blockIdx.x;
    const int m0 = blockIdx.y * 64, n0 = bx * 128;
    const int wm = (w >> 1) * 32, wn = (w & 1) * 64;
    floatx4 acc[2][4];
#pragma unroll
    for (int i = 0; i < 2; ++i)
#pragma unroll
        for (int j = 0; j < 4; ++j)
#pragma unroll
            for (int e = 0; e < 4; ++e) acc[i][j][e] = 0.f;

    auto STAGE = [&](int buf, int kt) {
        {   // A: 64 rows, one instr per wave
            int row = w * 16 + (l >> 2);
            int g = (l & 3) ^ (row & 3);
            gload_lds16(A + (size_t)(m0 + row) * 512 + kt + g * 8, &As[buf][w * 512]);
        }
#pragma unroll
        for (int r = 0; r < 2; ++r) {   // B: 128 rows, two instrs per wave
            int slot = r * 4 + w;
            int row = slot * 16 + (l >> 2);
            int g = (l & 3) ^ (row & 3);
            gload_lds16(BT + (size_t)(n0 + row) * 512 + kt + g * 8, &Bs[buf][slot * 512]);
        }
    };

    STAGE(0, 0);
    __syncthreads();
    for (int t = 0; t < 16; ++t) {
        int cur = t & 1;
        if (t < 15) STAGE(cur ^ 1, (t + 1) * 32);
        short8 a[2], b[4];
#pragma unroll
        for (int mi = 0; mi < 2; ++mi) {
            int row = wm + mi * 16 + l15;
            int p = l4 ^ (row & 3);
            a[mi] = *(const short8*)(&As[cur][row * 32 + p * 8]);
        }
#pragma unroll
        for (int ni = 0; ni < 4; ++ni) {
            int row = wn + ni * 16 + l15;
            int p = l4 ^ (row & 3);
            b[ni] = *(const short8*)(&Bs[cur][row * 32 + p * 8]);
        }
#pragma unroll
        for (int mi = 0; mi < 2; ++mi)
#pragma unroll
            for (int ni = 0; ni < 4; ++ni)
                acc[mi][ni] = mfma_bf16(a[mi], b[ni], acc[mi][ni]);
        __syncthreads();
    }
    const int region = bx >> 2;  // 0=Q 1=K 2=V
    const int cb = (bx & 3) * 128;
    if (region < 2) {
        us* outp = region == 0 ? Qg : Kg;
#pragma unroll
        for (int mi = 0; mi < 2; ++mi)
#pragma unroll
            for (int ni = 0; ni < 4; ++ni)
#pragma unroll
                for (int r = 0; r < 4; ++r) {
                    int row = m0 + wm + mi * 16 + l4 * 4 + r;
                    int col = cb + wn + ni * 16 + l15;
                    outp[(size_t)row * 512 + col] = f2bf(elu1(acc[mi][ni][r]));
                }
    } else {
        // V: write transposed VTg[chain][d][s], s-pairs packed into 4B stores
        const int hh = (bx & 3) * 2 + (w & 1);
#pragma unroll
        for (int mi = 0; mi < 2; ++mi) {
            int row0 = m0 + wm + mi * 16 + l4 * 4;  // even, %4==0
            int s0 = row0 >> 1;
#pragma unroll
            for (int ni = 0; ni < 4; ++ni) {
                int d = ni * 16 + l15;
#pragma unroll
                for (int b = 0; b < 2; ++b) {
                    unsigned int pk = (unsigned int)f2bf(acc[mi][ni][b]) |
                                      ((unsigned int)f2bf(acc[mi][ni][2 + b]) << 16);
                    *(unsigned int*)(VTg + ((size_t)((b * 8 + hh) * 80 + d)) * 2048 + s0) = pk;
                }
            }
        }
    }
}

// ---------------- per-chunk: C = [V^T;1] K^T  (V^T from VTg, coalesced) ----
__global__ __launch_bounds__(256)
void chunk_kv_kernel(const us* __restrict__ Kg, const us* __restrict__ VTg,
                     float* __restrict__ KVc) {
    __shared__ __align__(16) us VT_l[80 * 64];
    __shared__ __align__(16) us KT_l[64 * 72];
    const int c = blockIdx.x, chain = blockIdx.y;
    const int b = chain >> 3, hh = chain & 7;
    const int tid = threadIdx.x;
    const int w = tid >> 6, l = tid & 63;
    const int lrow = l >> 3, lg = l & 7;
    // stage V^T rows 0..79 (row 64 = ones from pack) with XOR part swizzle
#pragma unroll
    for (int r = 0; r < 3; ++r) {
        int slot = r * 4 + w;
        if (slot < 10) {
            int row = slot * 8 + lrow;
            int g = lg ^ (row & 7);
            gload_lds16(VTg + (size_t)(chain * 80 + row) * 2048 + c * 64 + g * 8,
                        VT_l + slot * 512);
        }
    }
    // K^T via scalar transpose (lane = dk)
#pragma unroll
    for (int gi = 0; gi < 2; ++gi) {
        int g = w + gi * 4;
        __align__(16) us kk[8];
#pragma unroll
        for (int e = 0; e < 8; ++e)
            kk[e] = Kg[(size_t)((c * 64 + g * 8 + e) * 2 + b) * 512 + hh * 64 + l];
        *(uint4*)(KT_l + l * 72 + g * 8) = *(uint4*)kk;
    }
    __syncthreads();
    const int l15 = l & 15, l4 = l >> 4;
    short8 af[5][2], bfr[2];
#pragma unroll
    for (int mi = 0; mi < 5; ++mi) {
        int row = mi * 16 + l15;
        int p = l4 ^ (row & 7);
        af[mi][0] = *(const short8*)(VT_l + row * 64 + p * 8);
        af[mi][1] = *(const short8*)(VT_l + row * 64 + (p ^ 4) * 8);
    }
    {
        int row = w * 16 + l15;
        bfr[0] = *(const short8*)(KT_l + row * 72 + l4 * 8);
        bfr[1] = *(const short8*)(KT_l + row * 72 + 32 + l4 * 8);
    }
    float* out = KVc + (size_t)(chain * 32 + c) * 4608;
#pragma unroll
    for (int mi = 0; mi < 5; ++mi) {
        floatx4 a = {0.f, 0.f, 0.f, 0.f};
        a = mfma_bf16(af[mi][0], bfr[0], a);
        a = mfma_bf16(af[mi][1], bfr[1], a);
#pragma unroll
        for (int r = 0; r < 4; ++r) {
            int row = mi * 16 + l4 * 4 + r;
            if (row < 65) out[row * 64 + w * 16 + l15] = a[r];
        }
    }
}

// ---------------- exclusive prefix over chunks -> bf16 MTg -----------------
__global__ __launch_bounds__(256)
void cumsum_kernel(const float* __restrict__ KVc, us* __restrict__ MTg) {
    const int chain = blockIdx.x, rg = blockIdx.y;
    const int row = rg * 4 + (threadIdx.x >> 6), col = threadIdx.x & 63;
    const float* in = KVc + (size_t)chain * 32 * 4608 + row * 64 + col;
    us* out = MTg + ((size_t)chain * 32 * 80 + row) * 64 + col;
    float acc = 0.f;
#pragma unroll 4
    for (int cc = 0; cc < 32; ++cc) {
        out[(size_t)cc * 5120] = f2bf(acc);
        acc += in[(size_t)cc * 4608];
    }
}

// ---------------- MFMA attention, split-phase staging ----------------------
__global__ __launch_bounds__(256)
void attn_kernel(const us* __restrict__ Qg, const us* __restrict__ Kg,
                 const us* __restrict__ VTg, const us* __restrict__ MTg,
                 us* __restrict__ ATT) {
    __shared__ __align__(16) us Qs[64 * 64];
    __shared__ __align__(16) us Ks[64 * 64];
    __shared__ __align__(16) us Vs[80 * 64];
    __shared__ __align__(16) us Ms[80 * 64];
    __shared__ __align__(16) us Sl[64 * 64];
    const int c = blockIdx.x, chain = blockIdx.y;
    const int b = chain >> 3, hh = chain & 7;
    const int tid = threadIdx.x;
    const int w = tid >> 6, l = tid & 63;
    const int l15 = l & 15, l4 = l >> 4;
    const int lrow = l >> 3, lg = l & 7;

    // issue Q,K staging (4 vm-ops/wave)
#pragma unroll
    for (int r = 0; r < 2; ++r) {
        int slot = r * 4 + w;
        int row = slot * 8 + lrow;
        int g = lg ^ (row & 7);
        size_t grow = (size_t)((c * 64 + row) * 2 + b) * 512 + hh * 64 + g * 8;
        gload_lds16(Qg + grow, Qs + slot * 512);
        gload_lds16(Kg + grow, Ks + slot * 512);
    }
    // issue V,M staging (5 vm-ops/wave, uniform)
#pragma unroll
    for (int i = 0; i < 5; ++i) {
        int p = w * 5 + i;
        int s = p < 10 ? p : p - 10;
        int row = s * 8 + lrow;
        int g = lg ^ (row & 7);
        if (p < 10)
            gload_lds16(VTg + (size_t)(chain * 80 + row) * 2048 + c * 64 + g * 8,
                        Vs + s * 512);
        else
            gload_lds16(MTg + ((size_t)(chain * 32 + c) * 80 + row) * 64 + g * 8,
                        Ms + s * 512);
    }
    // wait only for Q,K (oldest 4 of 9), then barrier
    asm volatile("s_waitcnt vmcnt(5)" ::: "memory");
    __builtin_amdgcn_sched_barrier(0);
    __builtin_amdgcn_s_barrier();

    short8 qf[2];
    {
        int row = w * 16 + l15, p = l4 ^ (row & 7);
        qf[0] = *(const short8*)(Qs + row * 64 + p * 8);
        qf[1] = *(const short8*)(Qs + row * 64 + (p ^ 4) * 8);
    }
    short8 kf[4][2];
#pragma unroll
    for (int ni = 0; ni < 4; ++ni) {
        int row = ni * 16 + l15, p = l4 ^ (row & 7);
        kf[ni][0] = *(const short8*)(Ks + row * 64 + p * 8);
        kf[ni][1] = *(const short8*)(Ks + row * 64 + (p ^ 4) * 8);
    }

    // S = Q @ K^T (causal) -> bf16 Sl ; V/M loads still in flight
    const int ibase = w * 16 + l4 * 4;
#pragma unroll
    for (int ni = 0; ni < 4; ++ni) {
        floatx4 s = {0.f, 0.f, 0.f, 0.f};
        s = mfma_bf16(qf[0], kf[ni][0], s);
        s = mfma_bf16(qf[1], kf[ni][1], s);
        int col = ni * 16 + l15;
#pragma unroll
        for (int r = 0; r < 4; ++r) {
            int i = ibase + r;
            float v = (col <= i) ? s[r] : 0.f;
            Sl[i * 64 + (((col >> 3) ^ (i & 7)) * 8) + (col & 7)] = f2bf(v);
        }
    }
    short8 sf[2];
    {
        int ir = w * 16 + l15;  // rows written by this wave only
        sf[0] = *(const short8*)(Sl + ir * 64 + ((l4 ^ (ir & 7)) * 8));
        sf[1] = *(const short8*)(Sl + ir * 64 + (((4 + l4) ^ (ir & 7)) * 8));
    }
    __syncthreads();  // drains vmcnt(0): V,M staged by all waves

    short8 vf[5][2], mf[5][2];
#pragma unroll
    for (int ni = 0; ni < 5; ++ni) {
        int row = ni * 16 + l15, p = l4 ^ (row & 7);
        vf[ni][0] = *(const short8*)(Vs + row * 64 + p * 8);
        vf[ni][1] = *(const short8*)(Vs + row * 64 + (p ^ 4) * 8);
        mf[ni][0] = *(const short8*)(Ms + row * 64 + p * 8);
        mf[ni][1] = *(const short8*)(Ms + row * 64 + (p ^ 4) * 8);
    }

    floatx4 acc[5];
#pragma unroll
    for (int ni = 0; ni < 5; ++ni) {
        floatx4 a = {0.f, 0.f, 0.f, 0.f};
        a = mfma_bf16(sf[0], vf[ni][0], a);
        a = mfma_bf16(sf[1], vf[ni][1], a);
        a = mfma_bf16(qf[0], mf[ni][0], a);
        a = mfma_bf16(qf[1], mf[ni][1], a);
        acc[ni] = a;
    }

    float fac[4];
#pragma unroll
    for (int r = 0; r < 4; ++r) {
        float den = __shfl(acc[4][r], l & 48, 64);
        fac[r] = SCALE / (SCALE * den + EPS);
    }
#pragma unroll
    for (int ni = 0; ni < 4; ++ni)
#pragma unroll
        for (int r = 0; r < 4; ++r) {
            int i = ibase + r;
            ATT[((size_t)((c * 64 + i) * 2 + b)) * 512 + hh * 64 + ni * 16 + l15] =
                f2bf(acc[ni][r] * fac[r]);
        }
}

// ---------------- fused Wo GEMM + residual + LayerNorm ---------------------
__global__ __launch_bounds__(256)
void wo_ln_kernel(const us* __restrict__ ATT, const us* __restrict__ WoT,
                  const float* __restrict__ h, const float* __restrict__ gamma,
                  const float* __restrict__ beta, float* __restrict__ out) {
    __shared__ __align__(16) us As[2][16 * 32];
    __shared__ __align__(16) us Bs[2][512 * 32];
    __shared__ float redS[4][16];
    __shared__ float redQ[4][16];
    __shared__ float mml[16], rsl[16];
    const int tid = threadIdx.x;
    const int w = tid >> 6, l = tid & 63;
    const int l15 = l & 15, l4 = l >> 4;
    const int m0 = blockIdx.x * 16, wn = w * 128;
    floatx4 acc[8];
#pragma unroll
    for (int j = 0; j < 8; ++j)
#pragma unroll
        for (int e = 0; e < 4; ++e) acc[j][e] = 0.f;

    auto STAGE = [&](int buf, int kt) {
#pragma unroll
        for (int r = 0; r < 8; ++r) {
            int slot = r * 4 + w;
            int row = slot * 16 + (l >> 2);
            int g = (l & 3) ^ (row & 3);
            gload_lds16(WoT + (size_t)row * 512 + kt + g * 8, &Bs[buf][slot * 512]);
        }
        if (w == 0) {
            int row = l >> 2;
            int g = (l & 3) ^ (row & 3);
            gload_lds16(ATT + (size_t)(m0 + row) * 512 + kt + g * 8, &As[buf][0]);
        }
    };

    STAGE(0, 0);
    __syncthreads();
    for (int t = 0; t < 16; ++t) {
        int cur = t & 1;
        if (t < 15) STAGE(cur ^ 1, (t + 1) * 32);
        short8 af, bf[8];
        {
            int row = l15, p = l4 ^ (row & 3);
            af = *(const short8*)(&As[cur][row * 32 + p * 8]);
        }
#pragma unroll
        for (int ni = 0; ni < 8; ++ni) {
            int row = wn + ni * 16 + l15, p = l4 ^ (row & 3);
            bf[ni] = *(const short8*)(&Bs[cur][row * 32 + p * 8]);
        }
#pragma unroll
        for (int ni = 0; ni < 8; ++ni)
            acc[ni] = mfma_bf16(af, bf[ni], acc[ni]);
        __syncthreads();
    }

#pragma unroll
    for (int r = 0; r < 4; ++r) {
        int row = l4 * 4 + r;
        const float* hrow = h + (size_t)(m0 + row) * 512 + wn + l15;
        float s = 0.f, q = 0.f;
#pragma unroll
        for (int ni = 0; ni < 8; ++ni) {
            float x = acc[ni][r] + hrow[ni * 16];
            acc[ni][r] = x;
            s += x;
            q = fmaf(x, x, q);
        }
#pragma unroll
        for (int off = 1; off <= 8; off <<= 1) {
            s += __shfl_xor(s, off, 64);
            q += __shfl_xor(q, off, 64);
        }
        if (l15 == 0) { redS[w][row] = s; redQ[w][row] = q; }
    }
    __syncthreads();
    if (tid < 16) {
        float s = redS[0][tid] + redS[1][tid] + redS[2][tid] + redS[3][tid];
        float q = redQ[0][tid] + redQ[1][tid] + redQ[2][tid] + redQ[3][tid];
        float mean = s * (1.f / 512);
        float var = q * (1.f / 512) - mean * mean;
        mml[tid] = mean;
        rsl[tid] = rsqrtf(var + LN_EPS);
    }
    __syncthreads();
#pragma unroll
    for (int r = 0; r < 4; ++r) {
        int row = l4 * 4 + r;
        float mean = mml[row], rstd = rsl[row];
#pragma unroll
        for (int ni = 0; ni < 8; ++ni) {
            int col = wn + ni * 16 + l15;
            out[(size_t)(m0 + row) * 512 + col] =
                (acc[ni][r] - mean) * rstd * gamma[col] + beta[col];
        }
    }
}

extern "C" void kernel_launch(void* const* d_in, const int* in_sizes, int n_in,
                              void* d_out, int out_size, void* d_ws, size_t ws_size,
                              hipStream_t stream) {
    const float* h = (const float*)d_in[0];
    const float* Wq = (const float*)d_in[1];
    const float* Wkv = (const float*)d_in[2];
    const float* Wo = (const float*)d_in[3];
    const float* gamma = (const float*)d_in[4];
    const float* beta = (const float*)d_in[5];

    char* ws = (char*)d_ws;
    us* Qg      = (us*)(ws + 0);          //  4 MB
    us* Kg      = (us*)(ws + 4194304);    //  4 MB
    us* VTg     = (us*)(ws + 12582912);   //  5.25 MB [16][80][2048]
    us* ATT     = (us*)(ws + 17825792);   //  4 MB
    us* WoT     = (us*)(ws + 22020096);   //  0.5 MB
    us* MTg     = (us*)(ws + 22544384);   //  5.25 MB [16][32][80][64]
    us* hB      = (us*)(ws + 27787264);   //  4 MB
    us* WqkvT   = (us*)(ws + 31981568);   //  1.5 MB
    float* KVc  = (float*)(ws + 33554432);//  9.44 MB

    dim3 blk(256);
    pack_kernel<<<2336, blk, 0, stream>>>(h, Wq, Wkv, Wo, hB, WqkvT, WoT, VTg);
    qkv_gemm<<<dim3(12, 64), blk, 0, stream>>>(hB, WqkvT, Qg, Kg, VTg);
    chunk_kv_kernel<<<dim3(32, 16), blk, 0, stream>>>(Kg, VTg, KVc);
    cumsum_kernel<<<dim3(16, 17), blk, 0, stream>>>(KVc, MTg);
    attn_kernel<<<dim3(32, 16), blk, 0, stream>>>(Qg, Kg, VTg, MTg, ATT);
    wo_ln_kernel<<<256, blk, 0, stream>>>(ATT, WoT, h, gamma, beta, (float*)d_out);
}